// Round 1
// baseline (1139.450 us; speedup 1.0000x reference)
//
#include <hip/hip_runtime.h>

constexpr int NN = 50000;   // nodes
constexpr int NE = 800000;  // edges (without self loops)

// ----------------------------- CSR build -----------------------------------
__global__ void hist_kernel(const int* __restrict__ dst, int* __restrict__ deg) {
    int e = blockIdx.x * blockDim.x + threadIdx.x;
    if (e < NE) atomicAdd(&deg[dst[e]], 1);
}

__global__ __launch_bounds__(1024) void scan_kernel(const int* __restrict__ deg,
                                                    int* __restrict__ row_ptr) {
    __shared__ int sd[1024];
    int tid = threadIdx.x;
    int carry = 0;
    for (int base = 0; base < NN; base += 1024) {
        int i = base + tid;
        int v = (i < NN) ? deg[i] : 0;
        sd[tid] = v;
        __syncthreads();
        for (int off = 1; off < 1024; off <<= 1) {
            int y = (tid >= off) ? sd[tid - off] : 0;
            __syncthreads();
            sd[tid] += y;
            __syncthreads();
        }
        if (i < NN) row_ptr[i] = carry + sd[tid] - v;  // exclusive
        carry += sd[1023];
        __syncthreads();  // protect sd before next chunk overwrites
    }
    if (tid == 0) row_ptr[NN] = carry;
}

__global__ void fill_kernel(const int* __restrict__ src, const int* __restrict__ dst,
                            const int* __restrict__ row_ptr, int* __restrict__ fillc,
                            int* __restrict__ col) {
    int e = blockIdx.x * blockDim.x + threadIdx.x;
    if (e < NE) {
        int d = dst[e];
        int p = atomicAdd(&fillc[d], 1);
        col[row_ptr[d] + p] = src[e];
    }
}

// ------------------------- per-conv transform: xw = x@W, t = x@U ------------
template <int CI, int CO>
__global__ __launch_bounds__(256) void transform_kernel(const float* __restrict__ x,
                                                        const float* __restrict__ W,
                                                        const float* __restrict__ U,
                                                        float* __restrict__ xw,
                                                        float* __restrict__ t) {
    constexpr int NC = 4 * CO;
    __shared__ float Ws[CI * NC];
    __shared__ float Us[CI * 4];
    for (int i = threadIdx.x; i < CI * NC; i += 256) Ws[i] = W[i];
    for (int i = threadIdx.x; i < CI * 4; i += 256) Us[i] = U[i];
    __syncthreads();
    int n = blockIdx.x * 256 + threadIdx.x;
    if (n >= NN) return;
    float xr[CI];
    const float4* xv = reinterpret_cast<const float4*>(x + (size_t)n * CI);
#pragma unroll
    for (int q = 0; q < CI / 4; q++) {
        float4 v = xv[q];
        xr[4 * q + 0] = v.x; xr[4 * q + 1] = v.y; xr[4 * q + 2] = v.z; xr[4 * q + 3] = v.w;
    }
    float4* xwv = reinterpret_cast<float4*>(xw + (size_t)n * NC);
    for (int j = 0; j < NC; j += 4) {
        float a0 = 0.f, a1 = 0.f, a2 = 0.f, a3 = 0.f;
#pragma unroll
        for (int k = 0; k < CI; k++) {
            float xk = xr[k];
            const float* w = &Ws[k * NC + j];
            a0 = fmaf(xk, w[0], a0); a1 = fmaf(xk, w[1], a1);
            a2 = fmaf(xk, w[2], a2); a3 = fmaf(xk, w[3], a3);
        }
        xwv[j >> 2] = make_float4(a0, a1, a2, a3);
    }
    float a0 = 0.f, a1 = 0.f, a2 = 0.f, a3 = 0.f;
#pragma unroll
    for (int k = 0; k < CI; k++) {
        float xk = xr[k];
        a0 = fmaf(xk, Us[k * 4 + 0], a0); a1 = fmaf(xk, Us[k * 4 + 1], a1);
        a2 = fmaf(xk, Us[k * 4 + 2], a2); a3 = fmaf(xk, Us[k * 4 + 3], a3);
    }
    reinterpret_cast<float4*>(t)[n] = make_float4(a0, a1, a2, a3);
}

// ----------------- per-conv aggregation (CSR gather, CO lanes / node) -------
template <int CO>
__global__ __launch_bounds__(256) void agg_kernel(const float* __restrict__ xw,
                                                  const float* __restrict__ t,
                                                  const float* __restrict__ cvec,
                                                  const float* __restrict__ bias,
                                                  const int* __restrict__ row_ptr,
                                                  const int* __restrict__ col,
                                                  float* __restrict__ out) {
    constexpr int PB = 256 / CO;
    int n = blockIdx.x * PB + (int)(threadIdx.x / CO);
    int lc = threadIdx.x % CO;
    if (n >= NN) return;
    float c0 = cvec[0], c1 = cvec[1], c2 = cvec[2], c3 = cvec[3];
    float4 td = reinterpret_cast<const float4*>(t)[n];
    // self loop: q = softmax(c)
    float m = fmaxf(fmaxf(c0, c1), fmaxf(c2, c3));
    float e0 = __expf(c0 - m), e1 = __expf(c1 - m), e2 = __expf(c2 - m), e3 = __expf(c3 - m);
    float inv = 1.f / (e0 + e1 + e2 + e3);
    const float* xn = xw + (size_t)n * 4 * CO + lc;
    float acc = (e0 * xn[0] + e1 * xn[CO] + e2 * xn[2 * CO] + e3 * xn[3 * CO]) * inv;
    int beg = row_ptr[n], end = row_ptr[n + 1];
    for (int e = beg; e < end; e++) {
        int s = col[e];
        float4 ts = reinterpret_cast<const float4*>(t)[s];
        float d0 = ts.x - td.x + c0, d1 = ts.y - td.y + c1;
        float d2 = ts.z - td.z + c2, d3 = ts.w - td.w + c3;
        float mm = fmaxf(fmaxf(d0, d1), fmaxf(d2, d3));
        float f0 = __expf(d0 - mm), f1 = __expf(d1 - mm);
        float f2 = __expf(d2 - mm), f3 = __expf(d3 - mm);
        float is = 1.f / (f0 + f1 + f2 + f3);
        const float* xs = xw + (size_t)s * 4 * CO + lc;
        acc = fmaf(f0 * xs[0] + f1 * xs[CO] + f2 * xs[2 * CO] + f3 * xs[3 * CO], is, acc);
    }
    float r = acc / (float)(end - beg + 1) + bias[lc];
    out[(size_t)n * CO + lc] = fmaxf(r, 0.f);
}

// ------------------------------- batch norm ---------------------------------
template <int C>
__global__ __launch_bounds__(256) void bn_reduce_kernel(const float* __restrict__ a,
                                                        float* __restrict__ stats) {
    constexpr int R = 256 / C;
    int cidx = threadIdx.x % C;
    int r = threadIdx.x / C;
    float s = 0.f, s2 = 0.f;
    for (int n = blockIdx.x * R + r; n < NN; n += gridDim.x * R) {
        float v = a[(size_t)n * C + cidx];
        s += v; s2 = fmaf(v, v, s2);
    }
    __shared__ float ls[256], ls2[256];
    ls[threadIdx.x] = s; ls2[threadIdx.x] = s2;
    __syncthreads();
    for (int off = 128; off >= C; off >>= 1) {
        if (threadIdx.x < off) {
            ls[threadIdx.x] += ls[threadIdx.x + off];
            ls2[threadIdx.x] += ls2[threadIdx.x + off];
        }
        __syncthreads();
    }
    if (threadIdx.x < C) {
        atomicAdd(&stats[cidx], ls[threadIdx.x]);
        atomicAdd(&stats[C + cidx], ls2[threadIdx.x]);
    }
}

template <int C>
__global__ __launch_bounds__(256) void bn_norm_kernel(const float* __restrict__ a,
                                                      const float* __restrict__ stats,
                                                      const float* __restrict__ g,
                                                      const float* __restrict__ be,
                                                      float* __restrict__ out) {
    int i = blockIdx.x * 256 + threadIdx.x;
    if (i >= NN * C) return;
    int cidx = i % C;
    float mean = stats[cidx] * (1.f / NN);
    float var = stats[C + cidx] * (1.f / NN) - mean * mean;
    float sc = rsqrtf(fmaxf(var, 0.f) + 1e-5f) * g[cidx];
    out[i] = (a[i] - mean) * sc + be[cidx];
}

// ------------------------------- MLP head -----------------------------------
// z = relu(concat(x1,x2,x3)) [N,128]; z1 = relu(z@lw1+lb1) [N,256]
__global__ __launch_bounds__(256) void lin1_kernel(const float* __restrict__ x1,
                                                   const float* __restrict__ x2,
                                                   const float* __restrict__ x3,
                                                   const float* __restrict__ lw,
                                                   const float* __restrict__ lb,
                                                   float* __restrict__ z1) {
    __shared__ float Ws[128 * 64];
    int j0 = blockIdx.y * 64;
    for (int i = threadIdx.x; i < 128 * 64; i += 256) {
        int k = i >> 6, jj = i & 63;
        Ws[i] = lw[k * 256 + j0 + jj];
    }
    __syncthreads();
    int n = blockIdx.x * 256 + threadIdx.x;
    if (n >= NN) return;
    float acc[64];
#pragma unroll
    for (int u = 0; u < 64; u++) acc[u] = lb[j0 + u];

    const float4* p1 = reinterpret_cast<const float4*>(x1 + (size_t)n * 32);
    for (int q = 0; q < 8; q++) {
        float4 v = p1[q];
        v.x = fmaxf(v.x, 0.f); v.y = fmaxf(v.y, 0.f); v.z = fmaxf(v.z, 0.f); v.w = fmaxf(v.w, 0.f);
        const float* w = &Ws[(q * 4) * 64];
#pragma unroll
        for (int u = 0; u < 64; u++) {
            acc[u] = fmaf(v.x, w[u], acc[u]);
            acc[u] = fmaf(v.y, w[64 + u], acc[u]);
            acc[u] = fmaf(v.z, w[128 + u], acc[u]);
            acc[u] = fmaf(v.w, w[192 + u], acc[u]);
        }
    }
    const float4* p2 = reinterpret_cast<const float4*>(x2 + (size_t)n * 32);
    for (int q = 0; q < 8; q++) {
        float4 v = p2[q];
        v.x = fmaxf(v.x, 0.f); v.y = fmaxf(v.y, 0.f); v.z = fmaxf(v.z, 0.f); v.w = fmaxf(v.w, 0.f);
        const float* w = &Ws[(32 + q * 4) * 64];
#pragma unroll
        for (int u = 0; u < 64; u++) {
            acc[u] = fmaf(v.x, w[u], acc[u]);
            acc[u] = fmaf(v.y, w[64 + u], acc[u]);
            acc[u] = fmaf(v.z, w[128 + u], acc[u]);
            acc[u] = fmaf(v.w, w[192 + u], acc[u]);
        }
    }
    const float4* p3 = reinterpret_cast<const float4*>(x3 + (size_t)n * 64);
    for (int q = 0; q < 16; q++) {
        float4 v = p3[q];
        v.x = fmaxf(v.x, 0.f); v.y = fmaxf(v.y, 0.f); v.z = fmaxf(v.z, 0.f); v.w = fmaxf(v.w, 0.f);
        const float* w = &Ws[(64 + q * 4) * 64];
#pragma unroll
        for (int u = 0; u < 64; u++) {
            acc[u] = fmaf(v.x, w[u], acc[u]);
            acc[u] = fmaf(v.y, w[64 + u], acc[u]);
            acc[u] = fmaf(v.z, w[128 + u], acc[u]);
            acc[u] = fmaf(v.w, w[192 + u], acc[u]);
        }
    }
    float4* o = reinterpret_cast<float4*>(z1 + (size_t)n * 256 + j0);
#pragma unroll
    for (int u4 = 0; u4 < 16; u4++) {
        o[u4] = make_float4(fmaxf(acc[4 * u4 + 0], 0.f), fmaxf(acc[4 * u4 + 1], 0.f),
                            fmaxf(acc[4 * u4 + 2], 0.f), fmaxf(acc[4 * u4 + 3], 0.f));
    }
}

// z2 = relu(z1@lw2+lb2) [N,64]
__global__ __launch_bounds__(256) void lin2_kernel(const float* __restrict__ z1,
                                                   const float* __restrict__ lw,
                                                   const float* __restrict__ lb,
                                                   float* __restrict__ z2) {
    __shared__ float Ws[256 * 32];
    int j0 = blockIdx.y * 32;
    for (int i = threadIdx.x; i < 256 * 32; i += 256) {
        int k = i >> 5, jj = i & 31;
        Ws[i] = lw[k * 64 + j0 + jj];
    }
    __syncthreads();
    int n = blockIdx.x * 256 + threadIdx.x;
    if (n >= NN) return;
    float acc[32];
#pragma unroll
    for (int u = 0; u < 32; u++) acc[u] = lb[j0 + u];
    const float4* zp = reinterpret_cast<const float4*>(z1 + (size_t)n * 256);
    for (int k4 = 0; k4 < 64; k4++) {
        float4 v = zp[k4];
        const float* w = &Ws[(k4 * 4) * 32];
#pragma unroll
        for (int u = 0; u < 32; u++) {
            acc[u] = fmaf(v.x, w[u], acc[u]);
            acc[u] = fmaf(v.y, w[32 + u], acc[u]);
            acc[u] = fmaf(v.z, w[64 + u], acc[u]);
            acc[u] = fmaf(v.w, w[96 + u], acc[u]);
        }
    }
    float4* o = reinterpret_cast<float4*>(z2 + (size_t)n * 64 + j0);
#pragma unroll
    for (int u4 = 0; u4 < 8; u4++) {
        o[u4] = make_float4(fmaxf(acc[4 * u4 + 0], 0.f), fmaxf(acc[4 * u4 + 1], 0.f),
                            fmaxf(acc[4 * u4 + 2], 0.f), fmaxf(acc[4 * u4 + 3], 0.f));
    }
}

// z3 = relu(z2@lw3+lb3) [N,16]; out = sigmoid(z3@lwo+lbo) [N,1]
__global__ __launch_bounds__(256) void lin3o_kernel(const float* __restrict__ z2,
                                                    const float* __restrict__ lw3,
                                                    const float* __restrict__ lb3,
                                                    const float* __restrict__ lwo,
                                                    const float* __restrict__ lbo,
                                                    float* __restrict__ out) {
    __shared__ float W3s[64 * 16];
    __shared__ float Wos[16];
    __shared__ float b3s[16];
    for (int i = threadIdx.x; i < 64 * 16; i += 256) W3s[i] = lw3[i];
    if (threadIdx.x < 16) { Wos[threadIdx.x] = lwo[threadIdx.x]; b3s[threadIdx.x] = lb3[threadIdx.x]; }
    __syncthreads();
    int n = blockIdx.x * 256 + threadIdx.x;
    if (n >= NN) return;
    float acc[16];
#pragma unroll
    for (int u = 0; u < 16; u++) acc[u] = b3s[u];
    const float4* zp = reinterpret_cast<const float4*>(z2 + (size_t)n * 64);
    for (int k4 = 0; k4 < 16; k4++) {
        float4 v = zp[k4];
        const float* w = &W3s[(k4 * 4) * 16];
#pragma unroll
        for (int u = 0; u < 16; u++) {
            acc[u] = fmaf(v.x, w[u], acc[u]);
            acc[u] = fmaf(v.y, w[16 + u], acc[u]);
            acc[u] = fmaf(v.z, w[32 + u], acc[u]);
            acc[u] = fmaf(v.w, w[48 + u], acc[u]);
        }
    }
    float s = lbo[0];
#pragma unroll
    for (int u = 0; u < 16; u++) s = fmaf(fmaxf(acc[u], 0.f), Wos[u], s);
    out[n] = 1.f / (1.f + __expf(-s));
}

// ------------------------------- launcher -----------------------------------
extern "C" void kernel_launch(void* const* d_in, const int* in_sizes, int n_in,
                              void* d_out, int out_size, void* d_ws, size_t ws_size,
                              hipStream_t stream) {
    const float* x = (const float*)d_in[0];
    const int* ei = (const int*)d_in[1];
    const int* esrc = ei;
    const int* edst = ei + NE;
    const float* W[6]; const float* U[6]; const float* C[6]; const float* B[6];
    for (int i = 0; i < 6; i++) {
        W[i] = (const float*)d_in[2 + 4 * i];
        U[i] = (const float*)d_in[3 + 4 * i];
        C[i] = (const float*)d_in[4 + 4 * i];
        B[i] = (const float*)d_in[5 + 4 * i];
    }
    const float* g1 = (const float*)d_in[26]; const float* be1 = (const float*)d_in[27];
    const float* g2 = (const float*)d_in[28]; const float* be2 = (const float*)d_in[29];
    const float* g3 = (const float*)d_in[30]; const float* be3 = (const float*)d_in[31];
    const float* lw1 = (const float*)d_in[32]; const float* lb1 = (const float*)d_in[33];
    const float* lw2 = (const float*)d_in[34]; const float* lb2 = (const float*)d_in[35];
    const float* lw3 = (const float*)d_in[36]; const float* lb3 = (const float*)d_in[37];
    const float* lwo = (const float*)d_in[38]; const float* lbo = (const float*)d_in[39];

    char* w = (char*)d_ws;
    size_t o = 0;
    auto take = [&](size_t bytes) -> char* {
        char* p = w + o;
        o = (o + bytes + 255) & ~(size_t)255;
        return p;
    };
    int* deg = (int*)take((size_t)NN * 4);
    int* fillc = (int*)take((size_t)NN * 4);
    float* stats = (float*)take(3 * 256 * 4);   // 3 regions of 256 floats
    size_t zero_bytes = o;                       // deg + fillc + stats contiguous from 0
    int* row_ptr = (int*)take((size_t)(NN + 1) * 4);
    int* colA = (int*)take((size_t)NE * 4);
    float* t = (float*)take((size_t)NN * 4 * 4);
    float* xw = (float*)take((size_t)NN * 256 * 4);
    float* h = (float*)take((size_t)NN * 16 * 4);
    float* x1 = (float*)take((size_t)NN * 32 * 4);
    float* x2 = (float*)take((size_t)NN * 32 * 4);
    float* x3 = (float*)take((size_t)NN * 64 * 4);
    float* xat = (float*)take((size_t)NN * 32 * 4);
    float* tmp = (float*)take((size_t)NN * 64 * 4);
    float* z1 = xw;   // xw free after conv6
    float* z2 = tmp;  // tmp free after bn3 normalize
    float* st0 = stats, *st1 = stats + 256, *st2 = stats + 512;

    hipMemsetAsync(d_ws, 0, zero_bytes, stream);

    const int EB = (NE + 255) / 256;       // 3125
    const int NB = (NN + 255) / 256;       // 196

    hist_kernel<<<EB, 256, 0, stream>>>(edst, deg);
    scan_kernel<<<1, 1024, 0, stream>>>(deg, row_ptr);
    fill_kernel<<<EB, 256, 0, stream>>>(esrc, edst, row_ptr, fillc, colA);

    // conv1: 16 -> 16
    transform_kernel<16, 16><<<NB, 256, 0, stream>>>(x, W[0], U[0], xw, t);
    agg_kernel<16><<<(NN + 15) / 16, 256, 0, stream>>>(xw, t, C[0], B[0], row_ptr, colA, h);
    // conv2: 16 -> 32, then BN1 -> x1
    transform_kernel<16, 32><<<NB, 256, 0, stream>>>(h, W[1], U[1], xw, t);
    agg_kernel<32><<<(NN + 7) / 8, 256, 0, stream>>>(xw, t, C[1], B[1], row_ptr, colA, tmp);
    bn_reduce_kernel<32><<<256, 256, 0, stream>>>(tmp, st0);
    bn_norm_kernel<32><<<(NN * 32 + 255) / 256, 256, 0, stream>>>(tmp, st0, g1, be1, x1);
    // conv3: 32 -> 32 -> xat
    transform_kernel<32, 32><<<NB, 256, 0, stream>>>(x1, W[2], U[2], xw, t);
    agg_kernel<32><<<(NN + 7) / 8, 256, 0, stream>>>(xw, t, C[2], B[2], row_ptr, colA, xat);
    // conv4: 32 -> 32, BN2 -> x2
    transform_kernel<32, 32><<<NB, 256, 0, stream>>>(xat, W[3], U[3], xw, t);
    agg_kernel<32><<<(NN + 7) / 8, 256, 0, stream>>>(xw, t, C[3], B[3], row_ptr, colA, tmp);
    bn_reduce_kernel<32><<<256, 256, 0, stream>>>(tmp, st1);
    bn_norm_kernel<32><<<(NN * 32 + 255) / 256, 256, 0, stream>>>(tmp, st1, g2, be2, x2);
    // conv5: 32 -> 32 -> xat
    transform_kernel<32, 32><<<NB, 256, 0, stream>>>(x2, W[4], U[4], xw, t);
    agg_kernel<32><<<(NN + 7) / 8, 256, 0, stream>>>(xw, t, C[4], B[4], row_ptr, colA, xat);
    // conv6: 32 -> 64, BN3 -> x3
    transform_kernel<32, 64><<<NB, 256, 0, stream>>>(xat, W[5], U[5], xw, t);
    agg_kernel<64><<<(NN + 3) / 4, 256, 0, stream>>>(xw, t, C[5], B[5], row_ptr, colA, tmp);
    bn_reduce_kernel<64><<<256, 256, 0, stream>>>(tmp, st2);
    bn_norm_kernel<64><<<(NN * 64 + 255) / 256, 256, 0, stream>>>(tmp, st2, g3, be3, x3);

    // MLP head
    lin1_kernel<<<dim3(NB, 4), 256, 0, stream>>>(x1, x2, x3, lw1, lb1, z1);
    lin2_kernel<<<dim3(NB, 2), 256, 0, stream>>>(z1, lw2, lb2, z2);
    lin3o_kernel<<<NB, 256, 0, stream>>>(z2, lw3, lb3, lwo, lbo, (float*)d_out);
}

// Round 2
// 1057.325 us; speedup vs baseline: 1.0777x; 1.0777x over previous
//
#include <hip/hip_runtime.h>

constexpr int NN = 50000;   // nodes
constexpr int NE = 800000;  // edges (without self loops)

__device__ inline ushort f2bf(float f) {           // RTNE float -> bf16 bits
    uint u = __float_as_uint(f);
    u += 0x7FFF + ((u >> 16) & 1);
    return (ushort)(u >> 16);
}
__device__ inline float bf2f(ushort h) { return __uint_as_float((uint)h << 16); }

// ----------------------------- CSR build -----------------------------------
__global__ void hist_kernel(const int* __restrict__ dst, int* __restrict__ deg) {
    int e = blockIdx.x * blockDim.x + threadIdx.x;
    if (e < NE) atomicAdd(&deg[dst[e]], 1);
}

__global__ __launch_bounds__(1024) void scan_kernel(const int* __restrict__ deg,
                                                    int* __restrict__ row_ptr) {
    __shared__ int sd[1024];
    int tid = threadIdx.x;
    int carry = 0;
    for (int base = 0; base < NN; base += 1024) {
        int i = base + tid;
        int v = (i < NN) ? deg[i] : 0;
        sd[tid] = v;
        __syncthreads();
        for (int off = 1; off < 1024; off <<= 1) {
            int y = (tid >= off) ? sd[tid - off] : 0;
            __syncthreads();
            sd[tid] += y;
            __syncthreads();
        }
        if (i < NN) row_ptr[i] = carry + sd[tid] - v;  // exclusive
        carry += sd[1023];
        __syncthreads();
    }
    if (tid == 0) row_ptr[NN] = carry;
}

__global__ void fill_kernel(const int* __restrict__ src, const int* __restrict__ dst,
                            const int* __restrict__ row_ptr, int* __restrict__ fillc,
                            int* __restrict__ col) {
    int e = blockIdx.x * blockDim.x + threadIdx.x;
    if (e < NE) {
        int d = dst[e];
        int p = atomicAdd(&fillc[d], 1);
        col[row_ptr[d] + p] = src[e];
    }
}

// ---------------- per-conv transform: xw = bf16(x@W), t = x@U ---------------
template <int CI, int CO>
__global__ __launch_bounds__(256) void transform_kernel(const float* __restrict__ x,
                                                        const float* __restrict__ W,
                                                        const float* __restrict__ U,
                                                        ushort* __restrict__ xw,
                                                        float* __restrict__ t) {
    constexpr int NC = 4 * CO;
    __shared__ float Ws[CI * NC];
    __shared__ float Us[CI * 4];
    for (int i = threadIdx.x; i < CI * NC; i += 256) Ws[i] = W[i];
    for (int i = threadIdx.x; i < CI * 4; i += 256) Us[i] = U[i];
    __syncthreads();
    int n = blockIdx.x * 256 + threadIdx.x;
    if (n >= NN) return;
    float xr[CI];
    const float4* xv = reinterpret_cast<const float4*>(x + (size_t)n * CI);
#pragma unroll
    for (int q = 0; q < CI / 4; q++) {
        float4 v = xv[q];
        xr[4 * q + 0] = v.x; xr[4 * q + 1] = v.y; xr[4 * q + 2] = v.z; xr[4 * q + 3] = v.w;
    }
    ushort4* xwv = reinterpret_cast<ushort4*>(xw + (size_t)n * NC);
    for (int j = 0; j < NC; j += 4) {
        float a0 = 0.f, a1 = 0.f, a2 = 0.f, a3 = 0.f;
#pragma unroll
        for (int k = 0; k < CI; k++) {
            float xk = xr[k];
            const float* w = &Ws[k * NC + j];
            a0 = fmaf(xk, w[0], a0); a1 = fmaf(xk, w[1], a1);
            a2 = fmaf(xk, w[2], a2); a3 = fmaf(xk, w[3], a3);
        }
        ushort4 p;
        p.x = f2bf(a0); p.y = f2bf(a1); p.z = f2bf(a2); p.w = f2bf(a3);
        xwv[j >> 2] = p;
    }
    float a0 = 0.f, a1 = 0.f, a2 = 0.f, a3 = 0.f;
#pragma unroll
    for (int k = 0; k < CI; k++) {
        float xk = xr[k];
        a0 = fmaf(xk, Us[k * 4 + 0], a0); a1 = fmaf(xk, Us[k * 4 + 1], a1);
        a2 = fmaf(xk, Us[k * 4 + 2], a2); a3 = fmaf(xk, Us[k * 4 + 3], a3);
    }
    reinterpret_cast<float4*>(t)[n] = make_float4(a0, a1, a2, a3);
}

// ----------------- per-conv aggregation (CSR gather, CO lanes / node) -------
template <int CO>
__global__ __launch_bounds__(256) void agg_kernel(const ushort* __restrict__ xw,
                                                  const float* __restrict__ t,
                                                  const float* __restrict__ cvec,
                                                  const float* __restrict__ bias,
                                                  const int* __restrict__ row_ptr,
                                                  const int* __restrict__ col,
                                                  float* __restrict__ out) {
    constexpr int PB = 256 / CO;
    int n = blockIdx.x * PB + (int)(threadIdx.x / CO);
    int lc = threadIdx.x % CO;
    if (n >= NN) return;
    float c0 = cvec[0], c1 = cvec[1], c2 = cvec[2], c3 = cvec[3];
    float4 td = reinterpret_cast<const float4*>(t)[n];
    // self loop: q = softmax(c)
    float m = fmaxf(fmaxf(c0, c1), fmaxf(c2, c3));
    float e0 = __expf(c0 - m), e1 = __expf(c1 - m), e2 = __expf(c2 - m), e3 = __expf(c3 - m);
    float inv = 1.f / (e0 + e1 + e2 + e3);
    const ushort* xn = xw + (size_t)n * 4 * CO + lc;
    float acc = (e0 * bf2f(xn[0]) + e1 * bf2f(xn[CO]) + e2 * bf2f(xn[2 * CO]) +
                 e3 * bf2f(xn[3 * CO])) * inv;
    int beg = row_ptr[n], end = row_ptr[n + 1];
    for (int e = beg; e < end; e++) {
        int s = col[e];
        float4 ts = reinterpret_cast<const float4*>(t)[s];
        float d0 = ts.x - td.x + c0, d1 = ts.y - td.y + c1;
        float d2 = ts.z - td.z + c2, d3 = ts.w - td.w + c3;
        float mm = fmaxf(fmaxf(d0, d1), fmaxf(d2, d3));
        float f0 = __expf(d0 - mm), f1 = __expf(d1 - mm);
        float f2 = __expf(d2 - mm), f3 = __expf(d3 - mm);
        float is = 1.f / (f0 + f1 + f2 + f3);
        const ushort* xs = xw + (size_t)s * 4 * CO + lc;
        acc = fmaf(f0 * bf2f(xs[0]) + f1 * bf2f(xs[CO]) + f2 * bf2f(xs[2 * CO]) +
                   f3 * bf2f(xs[3 * CO]), is, acc);
    }
    float r = acc / (float)(end - beg + 1) + bias[lc];
    out[(size_t)n * CO + lc] = fmaxf(r, 0.f);
}

// ------------------------------- batch norm ---------------------------------
template <int C>
__global__ __launch_bounds__(256) void bn_reduce_kernel(const float* __restrict__ a,
                                                        float* __restrict__ stats) {
    constexpr int R = 256 / C;
    int cidx = threadIdx.x % C;
    int r = threadIdx.x / C;
    float s = 0.f, s2 = 0.f;
    for (int n = blockIdx.x * R + r; n < NN; n += gridDim.x * R) {
        float v = a[(size_t)n * C + cidx];
        s += v; s2 = fmaf(v, v, s2);
    }
    __shared__ float ls[256], ls2[256];
    ls[threadIdx.x] = s; ls2[threadIdx.x] = s2;
    __syncthreads();
    for (int off = 128; off >= C; off >>= 1) {
        if (threadIdx.x < off) {
            ls[threadIdx.x] += ls[threadIdx.x + off];
            ls2[threadIdx.x] += ls2[threadIdx.x + off];
        }
        __syncthreads();
    }
    if (threadIdx.x < C) {
        atomicAdd(&stats[cidx], ls[threadIdx.x]);
        atomicAdd(&stats[C + cidx], ls2[threadIdx.x]);
    }
}

template <int C>
__global__ __launch_bounds__(256) void bn_norm_kernel(const float* __restrict__ a,
                                                      const float* __restrict__ stats,
                                                      const float* __restrict__ g,
                                                      const float* __restrict__ be,
                                                      float* __restrict__ out) {
    int i = blockIdx.x * 256 + threadIdx.x;
    if (i >= NN * C) return;
    int cidx = i % C;
    float mean = stats[cidx] * (1.f / NN);
    float var = stats[C + cidx] * (1.f / NN) - mean * mean;
    float sc = rsqrtf(fmaxf(var, 0.f) + 1e-5f) * g[cidx];
    out[i] = (a[i] - mean) * sc + be[cidx];
}

// ------------------------------- MLP head -----------------------------------
__global__ __launch_bounds__(256) void lin1_kernel(const float* __restrict__ x1,
                                                   const float* __restrict__ x2,
                                                   const float* __restrict__ x3,
                                                   const float* __restrict__ lw,
                                                   const float* __restrict__ lb,
                                                   float* __restrict__ z1) {
    __shared__ float Ws[128 * 64];
    int j0 = blockIdx.y * 64;
    for (int i = threadIdx.x; i < 128 * 64; i += 256) {
        int k = i >> 6, jj = i & 63;
        Ws[i] = lw[k * 256 + j0 + jj];
    }
    __syncthreads();
    int n = blockIdx.x * 256 + threadIdx.x;
    if (n >= NN) return;
    float acc[64];
#pragma unroll
    for (int u = 0; u < 64; u++) acc[u] = lb[j0 + u];

    const float4* p1 = reinterpret_cast<const float4*>(x1 + (size_t)n * 32);
    for (int q = 0; q < 8; q++) {
        float4 v = p1[q];
        v.x = fmaxf(v.x, 0.f); v.y = fmaxf(v.y, 0.f); v.z = fmaxf(v.z, 0.f); v.w = fmaxf(v.w, 0.f);
        const float* w = &Ws[(q * 4) * 64];
#pragma unroll
        for (int u = 0; u < 64; u++) {
            acc[u] = fmaf(v.x, w[u], acc[u]);
            acc[u] = fmaf(v.y, w[64 + u], acc[u]);
            acc[u] = fmaf(v.z, w[128 + u], acc[u]);
            acc[u] = fmaf(v.w, w[192 + u], acc[u]);
        }
    }
    const float4* p2 = reinterpret_cast<const float4*>(x2 + (size_t)n * 32);
    for (int q = 0; q < 8; q++) {
        float4 v = p2[q];
        v.x = fmaxf(v.x, 0.f); v.y = fmaxf(v.y, 0.f); v.z = fmaxf(v.z, 0.f); v.w = fmaxf(v.w, 0.f);
        const float* w = &Ws[(32 + q * 4) * 64];
#pragma unroll
        for (int u = 0; u < 64; u++) {
            acc[u] = fmaf(v.x, w[u], acc[u]);
            acc[u] = fmaf(v.y, w[64 + u], acc[u]);
            acc[u] = fmaf(v.z, w[128 + u], acc[u]);
            acc[u] = fmaf(v.w, w[192 + u], acc[u]);
        }
    }
    const float4* p3 = reinterpret_cast<const float4*>(x3 + (size_t)n * 64);
    for (int q = 0; q < 16; q++) {
        float4 v = p3[q];
        v.x = fmaxf(v.x, 0.f); v.y = fmaxf(v.y, 0.f); v.z = fmaxf(v.z, 0.f); v.w = fmaxf(v.w, 0.f);
        const float* w = &Ws[(64 + q * 4) * 64];
#pragma unroll
        for (int u = 0; u < 64; u++) {
            acc[u] = fmaf(v.x, w[u], acc[u]);
            acc[u] = fmaf(v.y, w[64 + u], acc[u]);
            acc[u] = fmaf(v.z, w[128 + u], acc[u]);
            acc[u] = fmaf(v.w, w[192 + u], acc[u]);
        }
    }
    float4* o = reinterpret_cast<float4*>(z1 + (size_t)n * 256 + j0);
#pragma unroll
    for (int u4 = 0; u4 < 16; u4++) {
        o[u4] = make_float4(fmaxf(acc[4 * u4 + 0], 0.f), fmaxf(acc[4 * u4 + 1], 0.f),
                            fmaxf(acc[4 * u4 + 2], 0.f), fmaxf(acc[4 * u4 + 3], 0.f));
    }
}

__global__ __launch_bounds__(256) void lin2_kernel(const float* __restrict__ z1,
                                                   const float* __restrict__ lw,
                                                   const float* __restrict__ lb,
                                                   float* __restrict__ z2) {
    __shared__ float Ws[256 * 32];
    int j0 = blockIdx.y * 32;
    for (int i = threadIdx.x; i < 256 * 32; i += 256) {
        int k = i >> 5, jj = i & 31;
        Ws[i] = lw[k * 64 + j0 + jj];
    }
    __syncthreads();
    int n = blockIdx.x * 256 + threadIdx.x;
    if (n >= NN) return;
    float acc[32];
#pragma unroll
    for (int u = 0; u < 32; u++) acc[u] = lb[j0 + u];
    const float4* zp = reinterpret_cast<const float4*>(z1 + (size_t)n * 256);
    for (int k4 = 0; k4 < 64; k4++) {
        float4 v = zp[k4];
        const float* w = &Ws[(k4 * 4) * 32];
#pragma unroll
        for (int u = 0; u < 32; u++) {
            acc[u] = fmaf(v.x, w[u], acc[u]);
            acc[u] = fmaf(v.y, w[32 + u], acc[u]);
            acc[u] = fmaf(v.z, w[64 + u], acc[u]);
            acc[u] = fmaf(v.w, w[96 + u], acc[u]);
        }
    }
    float4* o = reinterpret_cast<float4*>(z2 + (size_t)n * 64 + j0);
#pragma unroll
    for (int u4 = 0; u4 < 8; u4++) {
        o[u4] = make_float4(fmaxf(acc[4 * u4 + 0], 0.f), fmaxf(acc[4 * u4 + 1], 0.f),
                            fmaxf(acc[4 * u4 + 2], 0.f), fmaxf(acc[4 * u4 + 3], 0.f));
    }
}

__global__ __launch_bounds__(256) void lin3o_kernel(const float* __restrict__ z2,
                                                    const float* __restrict__ lw3,
                                                    const float* __restrict__ lb3,
                                                    const float* __restrict__ lwo,
                                                    const float* __restrict__ lbo,
                                                    float* __restrict__ out) {
    __shared__ float W3s[64 * 16];
    __shared__ float Wos[16];
    __shared__ float b3s[16];
    for (int i = threadIdx.x; i < 64 * 16; i += 256) W3s[i] = lw3[i];
    if (threadIdx.x < 16) { Wos[threadIdx.x] = lwo[threadIdx.x]; b3s[threadIdx.x] = lb3[threadIdx.x]; }
    __syncthreads();
    int n = blockIdx.x * 256 + threadIdx.x;
    if (n >= NN) return;
    float acc[16];
#pragma unroll
    for (int u = 0; u < 16; u++) acc[u] = b3s[u];
    const float4* zp = reinterpret_cast<const float4*>(z2 + (size_t)n * 64);
    for (int k4 = 0; k4 < 16; k4++) {
        float4 v = zp[k4];
        const float* w = &W3s[(k4 * 4) * 16];
#pragma unroll
        for (int u = 0; u < 16; u++) {
            acc[u] = fmaf(v.x, w[u], acc[u]);
            acc[u] = fmaf(v.y, w[16 + u], acc[u]);
            acc[u] = fmaf(v.z, w[32 + u], acc[u]);
            acc[u] = fmaf(v.w, w[48 + u], acc[u]);
        }
    }
    float s = lbo[0];
#pragma unroll
    for (int u = 0; u < 16; u++) s = fmaf(fmaxf(acc[u], 0.f), Wos[u], s);
    out[n] = 1.f / (1.f + __expf(-s));
}

// ------------------------------- launcher -----------------------------------
extern "C" void kernel_launch(void* const* d_in, const int* in_sizes, int n_in,
                              void* d_out, int out_size, void* d_ws, size_t ws_size,
                              hipStream_t stream) {
    const float* x = (const float*)d_in[0];
    const int* ei = (const int*)d_in[1];
    const int* esrc = ei;
    const int* edst = ei + NE;
    const float* W[6]; const float* U[6]; const float* C[6]; const float* B[6];
    for (int i = 0; i < 6; i++) {
        W[i] = (const float*)d_in[2 + 4 * i];
        U[i] = (const float*)d_in[3 + 4 * i];
        C[i] = (const float*)d_in[4 + 4 * i];
        B[i] = (const float*)d_in[5 + 4 * i];
    }
    const float* g1 = (const float*)d_in[26]; const float* be1 = (const float*)d_in[27];
    const float* g2 = (const float*)d_in[28]; const float* be2 = (const float*)d_in[29];
    const float* g3 = (const float*)d_in[30]; const float* be3 = (const float*)d_in[31];
    const float* lw1 = (const float*)d_in[32]; const float* lb1 = (const float*)d_in[33];
    const float* lw2 = (const float*)d_in[34]; const float* lb2 = (const float*)d_in[35];
    const float* lw3 = (const float*)d_in[36]; const float* lb3 = (const float*)d_in[37];
    const float* lwo = (const float*)d_in[38]; const float* lbo = (const float*)d_in[39];

    char* w = (char*)d_ws;
    size_t o = 0;
    auto take = [&](size_t bytes) -> char* {
        char* p = w + o;
        o = (o + bytes + 255) & ~(size_t)255;
        return p;
    };
    int* deg = (int*)take((size_t)NN * 4);
    int* fillc = (int*)take((size_t)NN * 4);
    float* stats = (float*)take(3 * 256 * 4);
    size_t zero_bytes = o;
    int* row_ptr = (int*)take((size_t)(NN + 1) * 4);
    int* colA = (int*)take((size_t)NE * 4);
    float* t = (float*)take((size_t)NN * 4 * 4);
    char* xw_raw = take((size_t)NN * 256 * 4);   // bf16 xw (<=25.6MB) aliased with fp32 z1
    ushort* xw = (ushort*)xw_raw;
    float* h = (float*)take((size_t)NN * 16 * 4);
    float* x1 = (float*)take((size_t)NN * 32 * 4);
    float* x2 = (float*)take((size_t)NN * 32 * 4);
    float* x3 = (float*)take((size_t)NN * 64 * 4);
    float* xat = (float*)take((size_t)NN * 32 * 4);
    float* tmp = (float*)take((size_t)NN * 64 * 4);
    float* z1 = (float*)xw_raw;  // xw free after conv6
    float* z2 = tmp;             // tmp free after bn3 normalize
    float* st0 = stats, *st1 = stats + 256, *st2 = stats + 512;

    hipMemsetAsync(d_ws, 0, zero_bytes, stream);

    const int EB = (NE + 255) / 256;
    const int NB = (NN + 255) / 256;

    hist_kernel<<<EB, 256, 0, stream>>>(edst, deg);
    scan_kernel<<<1, 1024, 0, stream>>>(deg, row_ptr);
    fill_kernel<<<EB, 256, 0, stream>>>(esrc, edst, row_ptr, fillc, colA);

    // conv1: 16 -> 16
    transform_kernel<16, 16><<<NB, 256, 0, stream>>>(x, W[0], U[0], xw, t);
    agg_kernel<16><<<(NN + 15) / 16, 256, 0, stream>>>(xw, t, C[0], B[0], row_ptr, colA, h);
    // conv2: 16 -> 32, then BN1 -> x1
    transform_kernel<16, 32><<<NB, 256, 0, stream>>>(h, W[1], U[1], xw, t);
    agg_kernel<32><<<(NN + 7) / 8, 256, 0, stream>>>(xw, t, C[1], B[1], row_ptr, colA, tmp);
    bn_reduce_kernel<32><<<256, 256, 0, stream>>>(tmp, st0);
    bn_norm_kernel<32><<<(NN * 32 + 255) / 256, 256, 0, stream>>>(tmp, st0, g1, be1, x1);
    // conv3: 32 -> 32 -> xat
    transform_kernel<32, 32><<<NB, 256, 0, stream>>>(x1, W[2], U[2], xw, t);
    agg_kernel<32><<<(NN + 7) / 8, 256, 0, stream>>>(xw, t, C[2], B[2], row_ptr, colA, xat);
    // conv4: 32 -> 32, BN2 -> x2
    transform_kernel<32, 32><<<NB, 256, 0, stream>>>(xat, W[3], U[3], xw, t);
    agg_kernel<32><<<(NN + 7) / 8, 256, 0, stream>>>(xw, t, C[3], B[3], row_ptr, colA, tmp);
    bn_reduce_kernel<32><<<256, 256, 0, stream>>>(tmp, st1);
    bn_norm_kernel<32><<<(NN * 32 + 255) / 256, 256, 0, stream>>>(tmp, st1, g2, be2, x2);
    // conv5: 32 -> 32 -> xat
    transform_kernel<32, 32><<<NB, 256, 0, stream>>>(x2, W[4], U[4], xw, t);
    agg_kernel<32><<<(NN + 7) / 8, 256, 0, stream>>>(xw, t, C[4], B[4], row_ptr, colA, xat);
    // conv6: 32 -> 64, BN3 -> x3
    transform_kernel<32, 64><<<NB, 256, 0, stream>>>(xat, W[5], U[5], xw, t);
    agg_kernel<64><<<(NN + 3) / 4, 256, 0, stream>>>(xw, t, C[5], B[5], row_ptr, colA, tmp);
    bn_reduce_kernel<64><<<256, 256, 0, stream>>>(tmp, st2);
    bn_norm_kernel<64><<<(NN * 64 + 255) / 256, 256, 0, stream>>>(tmp, st2, g3, be3, x3);

    // MLP head
    lin1_kernel<<<dim3(NB, 4), 256, 0, stream>>>(x1, x2, x3, lw1, lb1, z1);
    lin2_kernel<<<dim3(NB, 2), 256, 0, stream>>>(z1, lw2, lb2, z2);
    lin3o_kernel<<<NB, 256, 0, stream>>>(z2, lw3, lb3, lwo, lbo, (float*)d_out);
}

// Round 3
// 764.464 us; speedup vs baseline: 1.4905x; 1.3831x over previous
//
#include <hip/hip_runtime.h>

constexpr int NN = 50000;   // nodes
constexpr int NE = 800000;  // edges (without self loops)

typedef _Float16 h8 __attribute__((ext_vector_type(8)));

// ----------------------------- CSR build -----------------------------------
__global__ void hist_kernel(const int* __restrict__ dst, int* __restrict__ deg) {
    int e = blockIdx.x * blockDim.x + threadIdx.x;
    if (e < NE) atomicAdd(&deg[dst[e]], 1);
}

__global__ __launch_bounds__(1024) void scan_kernel(const int* __restrict__ deg,
                                                    int* __restrict__ row_ptr) {
    __shared__ int wsum[16];
    __shared__ int chunk_total;
    int tid = threadIdx.x, wid = tid >> 6, lane = tid & 63;
    int carry = 0;
    for (int base = 0; base < NN; base += 1024) {
        int i = base + tid;
        int v = (i < NN) ? deg[i] : 0;
        int x = v;
#pragma unroll
        for (int off = 1; off < 64; off <<= 1) {
            int y = __shfl_up(x, off, 64);
            if (lane >= off) x += y;
        }
        if (lane == 63) wsum[wid] = x;
        __syncthreads();
        if (wid == 0) {
            int wv = (lane < 16) ? wsum[lane] : 0;
#pragma unroll
            for (int off = 1; off < 16; off <<= 1) {
                int y = __shfl_up(wv, off, 64);
                if (lane >= off) wv += y;
            }
            if (lane < 16) wsum[lane] = wv;
            if (lane == 15) chunk_total = wv;
        }
        __syncthreads();
        int wprefix = (wid == 0) ? 0 : wsum[wid - 1];
        if (i < NN) row_ptr[i] = carry + wprefix + x - v;  // exclusive
        carry += chunk_total;
        __syncthreads();
    }
    if (tid == 0) row_ptr[NN] = carry;
}

__global__ void fill_kernel(const int* __restrict__ src, const int* __restrict__ dst,
                            const int* __restrict__ row_ptr, int* __restrict__ fillc,
                            int* __restrict__ col) {
    int e = blockIdx.x * blockDim.x + threadIdx.x;
    if (e < NE) {
        int d = dst[e];
        int p = atomicAdd(&fillc[d], 1);
        col[row_ptr[d] + p] = src[e];
    }
}

// -------------- prep: xh = fp16(x), t = x@U (per node) ----------------------
template <int CI>
__global__ __launch_bounds__(256) void prep_kernel(const float* __restrict__ x,
                                                   const float* __restrict__ U,
                                                   _Float16* __restrict__ xh,
                                                   float* __restrict__ t) {
    __shared__ float Us[CI * 4];
    for (int i = threadIdx.x; i < CI * 4; i += 256) Us[i] = U[i];
    __syncthreads();
    int n = blockIdx.x * 256 + threadIdx.x;
    if (n >= NN) return;
    float xr[CI];
    const float4* xv = reinterpret_cast<const float4*>(x + (size_t)n * CI);
#pragma unroll
    for (int q = 0; q < CI / 4; q++) {
        float4 v = xv[q];
        xr[4 * q + 0] = v.x; xr[4 * q + 1] = v.y; xr[4 * q + 2] = v.z; xr[4 * q + 3] = v.w;
    }
    h8* xo = reinterpret_cast<h8*>(xh + (size_t)n * CI);
#pragma unroll
    for (int q = 0; q < CI / 8; q++) {
        h8 hv;
#pragma unroll
        for (int u = 0; u < 8; u++) hv[u] = (_Float16)xr[8 * q + u];
        xo[q] = hv;
    }
    float a0 = 0.f, a1 = 0.f, a2 = 0.f, a3 = 0.f;
#pragma unroll
    for (int k = 0; k < CI; k++) {
        float xk = xr[k];
        a0 = fmaf(xk, Us[k * 4 + 0], a0); a1 = fmaf(xk, Us[k * 4 + 1], a1);
        a2 = fmaf(xk, Us[k * 4 + 2], a2); a3 = fmaf(xk, Us[k * 4 + 3], a3);
    }
    reinterpret_cast<float4*>(t)[n] = make_float4(a0, a1, a2, a3);
}

// --------- aggregation: y[n, h*CI+c] = (1/cnt) * sum_j q_jh * x_j[c] --------
// CI lanes per node; per chunk of CI edges each lane computes one edge's
// softmax (fp32, in-register), then shfl-broadcasts feed 4 FMAs per lane.
template <int CI>
__global__ __launch_bounds__(256) void agg_kernel(const _Float16* __restrict__ xh,
                                                  const float* __restrict__ t,
                                                  const float* __restrict__ cvec,
                                                  const int* __restrict__ row_ptr,
                                                  const int* __restrict__ col,
                                                  _Float16* __restrict__ y) {
    constexpr int PB = 256 / CI;
    static_assert(PB * CI == 256, "");
    int lane = threadIdx.x % CI;
    int n = blockIdx.x * PB + threadIdx.x / CI;
    if (n >= NN) return;
    float4 cv = *reinterpret_cast<const float4*>(cvec);
    // self-loop weights: softmax(c)
    float m = fmaxf(fmaxf(cv.x, cv.y), fmaxf(cv.z, cv.w));
    float s0 = __expf(cv.x - m), s1 = __expf(cv.y - m),
          s2 = __expf(cv.z - m), s3 = __expf(cv.w - m);
    float sinv = 1.f / (s0 + s1 + s2 + s3);
    float xself = (float)xh[(size_t)n * CI + lane];
    float a0 = s0 * sinv * xself, a1 = s1 * sinv * xself,
          a2 = s2 * sinv * xself, a3 = s3 * sinv * xself;
    float4 td = reinterpret_cast<const float4*>(t)[n];
    int beg = row_ptr[n], end = row_ptr[n + 1];
    for (int base = beg; base < end; base += CI) {
        int mcnt = end - base;
        if (mcnt > CI) mcnt = CI;
        int s = 0;
        float q0 = 0.f, q1 = 0.f, q2 = 0.f, q3 = 0.f;
        if (lane < mcnt) {
            s = col[base + lane];
            float4 ts = reinterpret_cast<const float4*>(t)[s];
            float d0 = ts.x - td.x + cv.x, d1 = ts.y - td.y + cv.y;
            float d2 = ts.z - td.z + cv.z, d3 = ts.w - td.w + cv.w;
            float mm = fmaxf(fmaxf(d0, d1), fmaxf(d2, d3));
            q0 = __expf(d0 - mm); q1 = __expf(d1 - mm);
            q2 = __expf(d2 - mm); q3 = __expf(d3 - mm);
            float is = 1.f / (q0 + q1 + q2 + q3);
            q0 *= is; q1 *= is; q2 *= is; q3 *= is;
        }
        for (int j = 0; j < mcnt; ++j) {
            int sj = __shfl(s, j, CI);
            float w0 = __shfl(q0, j, CI), w1 = __shfl(q1, j, CI);
            float w2 = __shfl(q2, j, CI), w3 = __shfl(q3, j, CI);
            float xv = (float)xh[(size_t)sj * CI + lane];
            a0 = fmaf(w0, xv, a0); a1 = fmaf(w1, xv, a1);
            a2 = fmaf(w2, xv, a2); a3 = fmaf(w3, xv, a3);
        }
    }
    float sc = 1.f / (float)(end - beg + 1);
    _Float16* yo = y + (size_t)n * 4 * CI + lane;
    yo[0]      = (_Float16)(a0 * sc);
    yo[CI]     = (_Float16)(a1 * sc);
    yo[2 * CI] = (_Float16)(a2 * sc);
    yo[3 * CI] = (_Float16)(a3 * sc);
}

// --------- dense: out = relu(y @ Wstk + b); Wstk[h*CI+c, o] = W[c, h*CO+o] --
template <int K, int CO>
__global__ __launch_bounds__(256) void dense_kernel(const _Float16* __restrict__ y,
                                                    const float* __restrict__ W,
                                                    const float* __restrict__ bias,
                                                    float* __restrict__ out) {
    constexpr int CIc = K / 4;
    __shared__ float Ws[K * CO];
    for (int i = threadIdx.x; i < K * CO; i += 256) {
        int k = i / CO, o2 = i % CO;
        int h = k / CIc, c = k % CIc;
        Ws[i] = W[c * 4 * CO + h * CO + o2];
    }
    __syncthreads();
    int n = blockIdx.x * 256 + threadIdx.x;
    if (n >= NN) return;
    float acc[CO];
#pragma unroll
    for (int u = 0; u < CO; u++) acc[u] = bias[u];
    const h8* yp = reinterpret_cast<const h8*>(y + (size_t)n * K);
    for (int k8 = 0; k8 < K / 8; k8++) {
        h8 v = yp[k8];
#pragma unroll
        for (int u = 0; u < 8; u++) {
            float vf = (float)v[u];
            const float* w = &Ws[(k8 * 8 + u) * CO];
#pragma unroll
            for (int o = 0; o < CO; o++) acc[o] = fmaf(vf, w[o], acc[o]);
        }
    }
    float4* op = reinterpret_cast<float4*>(out + (size_t)n * CO);
#pragma unroll
    for (int u4 = 0; u4 < CO / 4; u4++) {
        op[u4] = make_float4(fmaxf(acc[4 * u4 + 0], 0.f), fmaxf(acc[4 * u4 + 1], 0.f),
                             fmaxf(acc[4 * u4 + 2], 0.f), fmaxf(acc[4 * u4 + 3], 0.f));
    }
}

// ------------------------------- batch norm ---------------------------------
template <int C>
__global__ __launch_bounds__(256) void bn_reduce_kernel(const float* __restrict__ a,
                                                        float* __restrict__ stats) {
    constexpr int R = 256 / C;
    int cidx = threadIdx.x % C;
    int r = threadIdx.x / C;
    float s = 0.f, s2 = 0.f;
    for (int n = blockIdx.x * R + r; n < NN; n += gridDim.x * R) {
        float v = a[(size_t)n * C + cidx];
        s += v; s2 = fmaf(v, v, s2);
    }
    __shared__ float ls[256], ls2[256];
    ls[threadIdx.x] = s; ls2[threadIdx.x] = s2;
    __syncthreads();
    for (int off = 128; off >= C; off >>= 1) {
        if (threadIdx.x < off) {
            ls[threadIdx.x] += ls[threadIdx.x + off];
            ls2[threadIdx.x] += ls2[threadIdx.x + off];
        }
        __syncthreads();
    }
    if (threadIdx.x < C) {
        atomicAdd(&stats[cidx], ls[threadIdx.x]);
        atomicAdd(&stats[C + cidx], ls2[threadIdx.x]);
    }
}

template <int C>
__global__ __launch_bounds__(256) void bn_norm_kernel(const float* __restrict__ a,
                                                      const float* __restrict__ stats,
                                                      const float* __restrict__ g,
                                                      const float* __restrict__ be,
                                                      float* __restrict__ out) {
    int i = blockIdx.x * 256 + threadIdx.x;
    if (i >= NN * C) return;
    int cidx = i % C;
    float mean = stats[cidx] * (1.f / NN);
    float var = stats[C + cidx] * (1.f / NN) - mean * mean;
    float sc = rsqrtf(fmaxf(var, 0.f) + 1e-5f) * g[cidx];
    out[i] = (a[i] - mean) * sc + be[cidx];
}

// ------------------------------- MLP head -----------------------------------
__global__ __launch_bounds__(256) void lin1_kernel(const float* __restrict__ x1,
                                                   const float* __restrict__ x2,
                                                   const float* __restrict__ x3,
                                                   const float* __restrict__ lw,
                                                   const float* __restrict__ lb,
                                                   float* __restrict__ z1) {
    __shared__ float Ws[128 * 64];
    int j0 = blockIdx.y * 64;
    for (int i = threadIdx.x; i < 128 * 64; i += 256) {
        int k = i >> 6, jj = i & 63;
        Ws[i] = lw[k * 256 + j0 + jj];
    }
    __syncthreads();
    int n = blockIdx.x * 256 + threadIdx.x;
    if (n >= NN) return;
    float acc[64];
#pragma unroll
    for (int u = 0; u < 64; u++) acc[u] = lb[j0 + u];

    const float4* p1 = reinterpret_cast<const float4*>(x1 + (size_t)n * 32);
    for (int q = 0; q < 8; q++) {
        float4 v = p1[q];
        v.x = fmaxf(v.x, 0.f); v.y = fmaxf(v.y, 0.f); v.z = fmaxf(v.z, 0.f); v.w = fmaxf(v.w, 0.f);
        const float* w = &Ws[(q * 4) * 64];
#pragma unroll
        for (int u = 0; u < 64; u++) {
            acc[u] = fmaf(v.x, w[u], acc[u]);
            acc[u] = fmaf(v.y, w[64 + u], acc[u]);
            acc[u] = fmaf(v.z, w[128 + u], acc[u]);
            acc[u] = fmaf(v.w, w[192 + u], acc[u]);
        }
    }
    const float4* p2 = reinterpret_cast<const float4*>(x2 + (size_t)n * 32);
    for (int q = 0; q < 8; q++) {
        float4 v = p2[q];
        v.x = fmaxf(v.x, 0.f); v.y = fmaxf(v.y, 0.f); v.z = fmaxf(v.z, 0.f); v.w = fmaxf(v.w, 0.f);
        const float* w = &Ws[(32 + q * 4) * 64];
#pragma unroll
        for (int u = 0; u < 64; u++) {
            acc[u] = fmaf(v.x, w[u], acc[u]);
            acc[u] = fmaf(v.y, w[64 + u], acc[u]);
            acc[u] = fmaf(v.z, w[128 + u], acc[u]);
            acc[u] = fmaf(v.w, w[192 + u], acc[u]);
        }
    }
    const float4* p3 = reinterpret_cast<const float4*>(x3 + (size_t)n * 64);
    for (int q = 0; q < 16; q++) {
        float4 v = p3[q];
        v.x = fmaxf(v.x, 0.f); v.y = fmaxf(v.y, 0.f); v.z = fmaxf(v.z, 0.f); v.w = fmaxf(v.w, 0.f);
        const float* w = &Ws[(64 + q * 4) * 64];
#pragma unroll
        for (int u = 0; u < 64; u++) {
            acc[u] = fmaf(v.x, w[u], acc[u]);
            acc[u] = fmaf(v.y, w[64 + u], acc[u]);
            acc[u] = fmaf(v.z, w[128 + u], acc[u]);
            acc[u] = fmaf(v.w, w[192 + u], acc[u]);
        }
    }
    float4* o = reinterpret_cast<float4*>(z1 + (size_t)n * 256 + j0);
#pragma unroll
    for (int u4 = 0; u4 < 16; u4++) {
        o[u4] = make_float4(fmaxf(acc[4 * u4 + 0], 0.f), fmaxf(acc[4 * u4 + 1], 0.f),
                            fmaxf(acc[4 * u4 + 2], 0.f), fmaxf(acc[4 * u4 + 3], 0.f));
    }
}

__global__ __launch_bounds__(256) void lin2_kernel(const float* __restrict__ z1,
                                                   const float* __restrict__ lw,
                                                   const float* __restrict__ lb,
                                                   float* __restrict__ z2) {
    __shared__ float Ws[256 * 32];
    int j0 = blockIdx.y * 32;
    for (int i = threadIdx.x; i < 256 * 32; i += 256) {
        int k = i >> 5, jj = i & 31;
        Ws[i] = lw[k * 64 + j0 + jj];
    }
    __syncthreads();
    int n = blockIdx.x * 256 + threadIdx.x;
    if (n >= NN) return;
    float acc[32];
#pragma unroll
    for (int u = 0; u < 32; u++) acc[u] = lb[j0 + u];
    const float4* zp = reinterpret_cast<const float4*>(z1 + (size_t)n * 256);
    for (int k4 = 0; k4 < 64; k4++) {
        float4 v = zp[k4];
        const float* w = &Ws[(k4 * 4) * 32];
#pragma unroll
        for (int u = 0; u < 32; u++) {
            acc[u] = fmaf(v.x, w[u], acc[u]);
            acc[u] = fmaf(v.y, w[32 + u], acc[u]);
            acc[u] = fmaf(v.z, w[64 + u], acc[u]);
            acc[u] = fmaf(v.w, w[96 + u], acc[u]);
        }
    }
    float4* o = reinterpret_cast<float4*>(z2 + (size_t)n * 64 + j0);
#pragma unroll
    for (int u4 = 0; u4 < 8; u4++) {
        o[u4] = make_float4(fmaxf(acc[4 * u4 + 0], 0.f), fmaxf(acc[4 * u4 + 1], 0.f),
                            fmaxf(acc[4 * u4 + 2], 0.f), fmaxf(acc[4 * u4 + 3], 0.f));
    }
}

__global__ __launch_bounds__(256) void lin3o_kernel(const float* __restrict__ z2,
                                                    const float* __restrict__ lw3,
                                                    const float* __restrict__ lb3,
                                                    const float* __restrict__ lwo,
                                                    const float* __restrict__ lbo,
                                                    float* __restrict__ out) {
    __shared__ float W3s[64 * 16];
    __shared__ float Wos[16];
    __shared__ float b3s[16];
    for (int i = threadIdx.x; i < 64 * 16; i += 256) W3s[i] = lw3[i];
    if (threadIdx.x < 16) { Wos[threadIdx.x] = lwo[threadIdx.x]; b3s[threadIdx.x] = lb3[threadIdx.x]; }
    __syncthreads();
    int n = blockIdx.x * 256 + threadIdx.x;
    if (n >= NN) return;
    float acc[16];
#pragma unroll
    for (int u = 0; u < 16; u++) acc[u] = b3s[u];
    const float4* zp = reinterpret_cast<const float4*>(z2 + (size_t)n * 64);
    for (int k4 = 0; k4 < 16; k4++) {
        float4 v = zp[k4];
        const float* w = &W3s[(k4 * 4) * 16];
#pragma unroll
        for (int u = 0; u < 16; u++) {
            acc[u] = fmaf(v.x, w[u], acc[u]);
            acc[u] = fmaf(v.y, w[16 + u], acc[u]);
            acc[u] = fmaf(v.z, w[32 + u], acc[u]);
            acc[u] = fmaf(v.w, w[48 + u], acc[u]);
        }
    }
    float s = lbo[0];
#pragma unroll
    for (int u = 0; u < 16; u++) s = fmaf(fmaxf(acc[u], 0.f), Wos[u], s);
    out[n] = 1.f / (1.f + __expf(-s));
}

// ------------------------------- launcher -----------------------------------
extern "C" void kernel_launch(void* const* d_in, const int* in_sizes, int n_in,
                              void* d_out, int out_size, void* d_ws, size_t ws_size,
                              hipStream_t stream) {
    const float* x = (const float*)d_in[0];
    const int* ei = (const int*)d_in[1];
    const int* esrc = ei;
    const int* edst = ei + NE;
    const float* W[6]; const float* U[6]; const float* C[6]; const float* B[6];
    for (int i = 0; i < 6; i++) {
        W[i] = (const float*)d_in[2 + 4 * i];
        U[i] = (const float*)d_in[3 + 4 * i];
        C[i] = (const float*)d_in[4 + 4 * i];
        B[i] = (const float*)d_in[5 + 4 * i];
    }
    const float* g1 = (const float*)d_in[26]; const float* be1 = (const float*)d_in[27];
    const float* g2 = (const float*)d_in[28]; const float* be2 = (const float*)d_in[29];
    const float* g3 = (const float*)d_in[30]; const float* be3 = (const float*)d_in[31];
    const float* lw1 = (const float*)d_in[32]; const float* lb1 = (const float*)d_in[33];
    const float* lw2 = (const float*)d_in[34]; const float* lb2 = (const float*)d_in[35];
    const float* lw3 = (const float*)d_in[36]; const float* lb3 = (const float*)d_in[37];
    const float* lwo = (const float*)d_in[38]; const float* lbo = (const float*)d_in[39];

    char* w = (char*)d_ws;
    size_t o = 0;
    auto take = [&](size_t bytes) -> char* {
        char* p = w + o;
        o = (o + bytes + 255) & ~(size_t)255;
        return p;
    };
    int* deg = (int*)take((size_t)NN * 4);
    int* fillc = (int*)take((size_t)NN * 4);
    float* stats = (float*)take(3 * 256 * 4);
    size_t zero_bytes = o;
    int* row_ptr = (int*)take((size_t)(NN + 1) * 4);
    int* colA = (int*)take((size_t)NE * 4);
    float* t = (float*)take((size_t)NN * 4 * 4);
    _Float16* xh = (_Float16*)take((size_t)NN * 32 * 2);
    char* A = take((size_t)NN * 256 * 4);       // y (fp16 [N,128]) then z1 (fp32 [N,256])
    _Float16* y = (_Float16*)A;
    float* z1 = (float*)A;
    float* xat = (float*)take((size_t)NN * 32 * 4);  // conv1/3/5 outputs
    float* x1 = (float*)take((size_t)NN * 32 * 4);
    float* x2 = (float*)take((size_t)NN * 32 * 4);
    float* x3 = (float*)take((size_t)NN * 64 * 4);
    float* tmp = (float*)take((size_t)NN * 64 * 4);
    float* z2 = tmp;
    float* st0 = stats, *st1 = stats + 256, *st2 = stats + 512;

    hipMemsetAsync(d_ws, 0, zero_bytes, stream);

    const int EB = (NE + 255) / 256;
    const int NB = (NN + 255) / 256;

    hist_kernel<<<EB, 256, 0, stream>>>(edst, deg);
    scan_kernel<<<1, 1024, 0, stream>>>(deg, row_ptr);
    fill_kernel<<<EB, 256, 0, stream>>>(esrc, edst, row_ptr, fillc, colA);

    // conv1: 16 -> 16  (out -> xat)
    prep_kernel<16><<<NB, 256, 0, stream>>>(x, U[0], xh, t);
    agg_kernel<16><<<(NN + 15) / 16, 256, 0, stream>>>(xh, t, C[0], row_ptr, colA, y);
    dense_kernel<64, 16><<<NB, 256, 0, stream>>>(y, W[0], B[0], xat);
    // conv2: 16 -> 32, BN1 -> x1
    prep_kernel<16><<<NB, 256, 0, stream>>>(xat, U[1], xh, t);
    agg_kernel<16><<<(NN + 15) / 16, 256, 0, stream>>>(xh, t, C[1], row_ptr, colA, y);
    dense_kernel<64, 32><<<NB, 256, 0, stream>>>(y, W[1], B[1], tmp);
    bn_reduce_kernel<32><<<256, 256, 0, stream>>>(tmp, st0);
    bn_norm_kernel<32><<<(NN * 32 + 255) / 256, 256, 0, stream>>>(tmp, st0, g1, be1, x1);
    // conv3: 32 -> 32 (out -> xat)
    prep_kernel<32><<<NB, 256, 0, stream>>>(x1, U[2], xh, t);
    agg_kernel<32><<<(NN + 7) / 8, 256, 0, stream>>>(xh, t, C[2], row_ptr, colA, y);
    dense_kernel<128, 32><<<NB, 256, 0, stream>>>(y, W[2], B[2], xat);
    // conv4: 32 -> 32, BN2 -> x2
    prep_kernel<32><<<NB, 256, 0, stream>>>(xat, U[3], xh, t);
    agg_kernel<32><<<(NN + 7) / 8, 256, 0, stream>>>(xh, t, C[3], row_ptr, colA, y);
    dense_kernel<128, 32><<<NB, 256, 0, stream>>>(y, W[3], B[3], tmp);
    bn_reduce_kernel<32><<<256, 256, 0, stream>>>(tmp, st1);
    bn_norm_kernel<32><<<(NN * 32 + 255) / 256, 256, 0, stream>>>(tmp, st1, g2, be2, x2);
    // conv5: 32 -> 32 (out -> xat)
    prep_kernel<32><<<NB, 256, 0, stream>>>(x2, U[4], xh, t);
    agg_kernel<32><<<(NN + 7) / 8, 256, 0, stream>>>(xh, t, C[4], row_ptr, colA, y);
    dense_kernel<128, 32><<<NB, 256, 0, stream>>>(y, W[4], B[4], xat);
    // conv6: 32 -> 64, BN3 -> x3
    prep_kernel<32><<<NB, 256, 0, stream>>>(xat, U[5], xh, t);
    agg_kernel<32><<<(NN + 7) / 8, 256, 0, stream>>>(xh, t, C[5], row_ptr, colA, y);
    dense_kernel<128, 64><<<NB, 256, 0, stream>>>(y, W[5], B[5], tmp);
    bn_reduce_kernel<64><<<256, 256, 0, stream>>>(tmp, st2);
    bn_norm_kernel<64><<<(NN * 64 + 255) / 256, 256, 0, stream>>>(tmp, st2, g3, be3, x3);

    // MLP head
    lin1_kernel<<<dim3(NB, 4), 256, 0, stream>>>(x1, x2, x3, lw1, lb1, z1);
    lin2_kernel<<<dim3(NB, 2), 256, 0, stream>>>(z1, lw2, lb2, z2);
    lin3o_kernel<<<NB, 256, 0, stream>>>(z2, lw3, lb3, lwo, lbo, (float*)d_out);
}

// Round 4
// 752.788 us; speedup vs baseline: 1.5136x; 1.0155x over previous
//
#include <hip/hip_runtime.h>

constexpr int NN = 50000;   // nodes
constexpr int NE = 800000;  // edges (without self loops)

typedef _Float16 h8 __attribute__((ext_vector_type(8)));
typedef _Float16 h4v __attribute__((ext_vector_type(4)));

// ----------------------------- CSR build -----------------------------------
__global__ void hist_kernel(const int* __restrict__ dst, int* __restrict__ deg) {
    int e = blockIdx.x * blockDim.x + threadIdx.x;
    if (e < NE) atomicAdd(&deg[dst[e]], 1);
}

__global__ __launch_bounds__(1024) void scan_kernel(const int* __restrict__ deg,
                                                    int* __restrict__ row_ptr) {
    __shared__ int wsum[16];
    __shared__ int chunk_total;
    int tid = threadIdx.x, wid = tid >> 6, lane = tid & 63;
    int carry = 0;
    for (int base = 0; base < NN; base += 1024) {
        int i = base + tid;
        int v = (i < NN) ? deg[i] : 0;
        int x = v;
#pragma unroll
        for (int off = 1; off < 64; off <<= 1) {
            int y = __shfl_up(x, off, 64);
            if (lane >= off) x += y;
        }
        if (lane == 63) wsum[wid] = x;
        __syncthreads();
        if (wid == 0) {
            int wv = (lane < 16) ? wsum[lane] : 0;
#pragma unroll
            for (int off = 1; off < 16; off <<= 1) {
                int y = __shfl_up(wv, off, 64);
                if (lane >= off) wv += y;
            }
            if (lane < 16) wsum[lane] = wv;
            if (lane == 15) chunk_total = wv;
        }
        __syncthreads();
        int wprefix = (wid == 0) ? 0 : wsum[wid - 1];
        if (i < NN) row_ptr[i] = carry + wprefix + x - v;  // exclusive
        carry += chunk_total;
        __syncthreads();
    }
    if (tid == 0) row_ptr[NN] = carry;
}

__global__ void fill_kernel(const int* __restrict__ src, const int* __restrict__ dst,
                            const int* __restrict__ row_ptr, int* __restrict__ fillc,
                            int* __restrict__ col, int* __restrict__ dstc) {
    int e = blockIdx.x * blockDim.x + threadIdx.x;
    if (e < NE) {
        int d = dst[e];
        int p = atomicAdd(&fillc[d], 1);
        int k = row_ptr[d] + p;
        col[k] = src[e];
        dstc[k] = d;
    }
}

// -------------- prep (conv1 only): xh = fp16(x), t = x@U --------------------
template <int CI>
__global__ __launch_bounds__(256) void prep_kernel(const float* __restrict__ x,
                                                   const float* __restrict__ U,
                                                   _Float16* __restrict__ xh,
                                                   float* __restrict__ t) {
    __shared__ float Us[CI * 4];
    for (int i = threadIdx.x; i < CI * 4; i += 256) Us[i] = U[i];
    __syncthreads();
    int n = blockIdx.x * 256 + threadIdx.x;
    if (n >= NN) return;
    float xr[CI];
    const float4* xv = reinterpret_cast<const float4*>(x + (size_t)n * CI);
#pragma unroll
    for (int q = 0; q < CI / 4; q++) {
        float4 v = xv[q];
        xr[4 * q + 0] = v.x; xr[4 * q + 1] = v.y; xr[4 * q + 2] = v.z; xr[4 * q + 3] = v.w;
    }
    h8* xo = reinterpret_cast<h8*>(xh + (size_t)n * CI);
#pragma unroll
    for (int q = 0; q < CI / 8; q++) {
        h8 hv;
#pragma unroll
        for (int u = 0; u < 8; u++) hv[u] = (_Float16)xr[8 * q + u];
        xo[q] = hv;
    }
    float a0 = 0.f, a1 = 0.f, a2 = 0.f, a3 = 0.f;
#pragma unroll
    for (int k = 0; k < CI; k++) {
        float xk = xr[k];
        a0 = fmaf(xk, Us[k * 4 + 0], a0); a1 = fmaf(xk, Us[k * 4 + 1], a1);
        a2 = fmaf(xk, Us[k * 4 + 2], a2); a3 = fmaf(xk, Us[k * 4 + 3], a3);
    }
    reinterpret_cast<float4*>(t)[n] = make_float4(a0, a1, a2, a3);
}

// ----------------- phase A: per-edge softmax weights (fp16 x4) --------------
__global__ __launch_bounds__(256) void edgeq_kernel(const int* __restrict__ col,
                                                    const int* __restrict__ dstc,
                                                    const float* __restrict__ t,
                                                    const float* __restrict__ cvec,
                                                    h4v* __restrict__ qbuf) {
    int k = blockIdx.x * 256 + threadIdx.x;
    if (k >= NE) return;
    int s = col[k], d = dstc[k];
    float4 ts = reinterpret_cast<const float4*>(t)[s];
    float4 td = reinterpret_cast<const float4*>(t)[d];
    float4 cv = *reinterpret_cast<const float4*>(cvec);
    float d0 = ts.x - td.x + cv.x, d1 = ts.y - td.y + cv.y;
    float d2 = ts.z - td.z + cv.z, d3 = ts.w - td.w + cv.w;
    float mm = fmaxf(fmaxf(d0, d1), fmaxf(d2, d3));
    float q0 = __expf(d0 - mm), q1 = __expf(d1 - mm);
    float q2 = __expf(d2 - mm), q3 = __expf(d3 - mm);
    float is = 1.f / (q0 + q1 + q2 + q3);
    h4v q;
    q[0] = (_Float16)(q0 * is); q[1] = (_Float16)(q1 * is);
    q[2] = (_Float16)(q2 * is); q[3] = (_Float16)(q3 * is);
    qbuf[k] = q;
}

// --------- phase B: y[n, h*CI+c] = (1/cnt) * sum_j q_jh * x_j[c] ------------
template <int CI>
__global__ __launch_bounds__(256) void aggB_kernel(const _Float16* __restrict__ xh,
                                                   const h4v* __restrict__ qbuf,
                                                   const float* __restrict__ cvec,
                                                   const int* __restrict__ row_ptr,
                                                   const int* __restrict__ col,
                                                   _Float16* __restrict__ y) {
    constexpr int PB = 256 / CI;
    int lane = threadIdx.x % CI;
    int n = blockIdx.x * PB + threadIdx.x / CI;
    if (n >= NN) return;
    float4 cv = *reinterpret_cast<const float4*>(cvec);
    float m = fmaxf(fmaxf(cv.x, cv.y), fmaxf(cv.z, cv.w));
    float s0 = __expf(cv.x - m), s1 = __expf(cv.y - m),
          s2 = __expf(cv.z - m), s3 = __expf(cv.w - m);
    float sinv = 1.f / (s0 + s1 + s2 + s3);
    float xself = (float)xh[(size_t)n * CI + lane];
    float a0 = s0 * sinv * xself, a1 = s1 * sinv * xself,
          a2 = s2 * sinv * xself, a3 = s3 * sinv * xself;
    int beg = row_ptr[n], end = row_ptr[n + 1];
#pragma unroll 8
    for (int e = beg; e < end; ++e) {
        int s = col[e];                 // uniform in lane-group -> broadcast
        h4v q = qbuf[e];                // broadcast
        float xv = (float)xh[(size_t)s * CI + lane];  // coalesced gather
        a0 = fmaf((float)q[0], xv, a0); a1 = fmaf((float)q[1], xv, a1);
        a2 = fmaf((float)q[2], xv, a2); a3 = fmaf((float)q[3], xv, a3);
    }
    float sc = 1.f / (float)(end - beg + 1);
    _Float16* yo = y + (size_t)n * 4 * CI + lane;
    yo[0]      = (_Float16)(a0 * sc);
    yo[CI]     = (_Float16)(a1 * sc);
    yo[2 * CI] = (_Float16)(a2 * sc);
    yo[3 * CI] = (_Float16)(a3 * sc);
}

// --------- dense: r = relu(y @ Wstk + b); PREP: also xh=fp16(r), t=r@U ------
template <int K, int CO, bool PREP>
__global__ __launch_bounds__(256) void dense_kernel(const _Float16* __restrict__ y,
                                                    const float* __restrict__ W,
                                                    const float* __restrict__ bias,
                                                    const float* __restrict__ U,
                                                    float* __restrict__ out,
                                                    _Float16* __restrict__ xh,
                                                    float* __restrict__ t) {
    constexpr int CIc = K / 4;
    __shared__ float Ws[K * CO];
    __shared__ float Us[PREP ? CO * 4 : 4];
    for (int i = threadIdx.x; i < K * CO; i += 256) {
        int k = i / CO, o2 = i % CO;
        int h = k / CIc, c = k % CIc;
        Ws[i] = W[c * 4 * CO + h * CO + o2];
    }
    if constexpr (PREP) {
        for (int i = threadIdx.x; i < CO * 4; i += 256) Us[i] = U[i];
    }
    __syncthreads();
    int n = blockIdx.x * 256 + threadIdx.x;
    if (n >= NN) return;
    float acc[CO];
#pragma unroll
    for (int u = 0; u < CO; u++) acc[u] = bias[u];
    const h8* yp = reinterpret_cast<const h8*>(y + (size_t)n * K);
    for (int k8 = 0; k8 < K / 8; k8++) {
        h8 v = yp[k8];
#pragma unroll
        for (int u = 0; u < 8; u++) {
            float vf = (float)v[u];
            const float* w = &Ws[(k8 * 8 + u) * CO];
#pragma unroll
            for (int o = 0; o < CO; o++) acc[o] = fmaf(vf, w[o], acc[o]);
        }
    }
#pragma unroll
    for (int u = 0; u < CO; u++) acc[u] = fmaxf(acc[u], 0.f);
    if constexpr (PREP) {
        h8* xo = reinterpret_cast<h8*>(xh + (size_t)n * CO);
#pragma unroll
        for (int q8 = 0; q8 < CO / 8; q8++) {
            h8 hv;
#pragma unroll
            for (int u = 0; u < 8; u++) hv[u] = (_Float16)acc[q8 * 8 + u];
            xo[q8] = hv;
        }
        float t0 = 0.f, t1 = 0.f, t2 = 0.f, t3 = 0.f;
#pragma unroll
        for (int o = 0; o < CO; o++) {
            float r = acc[o];
            t0 = fmaf(r, Us[o * 4 + 0], t0); t1 = fmaf(r, Us[o * 4 + 1], t1);
            t2 = fmaf(r, Us[o * 4 + 2], t2); t3 = fmaf(r, Us[o * 4 + 3], t3);
        }
        reinterpret_cast<float4*>(t)[n] = make_float4(t0, t1, t2, t3);
    } else {
        float4* op = reinterpret_cast<float4*>(out + (size_t)n * CO);
#pragma unroll
        for (int u4 = 0; u4 < CO / 4; u4++)
            op[u4] = make_float4(acc[4 * u4 + 0], acc[4 * u4 + 1],
                                 acc[4 * u4 + 2], acc[4 * u4 + 3]);
    }
}

// ------------------------------- batch norm ---------------------------------
template <int C>
__global__ __launch_bounds__(256) void bn_reduce_kernel(const float* __restrict__ a,
                                                        float* __restrict__ stats) {
    constexpr int R = 256 / C;
    int cidx = threadIdx.x % C;
    int r = threadIdx.x / C;
    float s = 0.f, s2 = 0.f;
    for (int n = blockIdx.x * R + r; n < NN; n += gridDim.x * R) {
        float v = a[(size_t)n * C + cidx];
        s += v; s2 = fmaf(v, v, s2);
    }
    __shared__ float ls[256], ls2[256];
    ls[threadIdx.x] = s; ls2[threadIdx.x] = s2;
    __syncthreads();
    for (int off = 128; off >= C; off >>= 1) {
        if (threadIdx.x < off) {
            ls[threadIdx.x] += ls[threadIdx.x + off];
            ls2[threadIdx.x] += ls2[threadIdx.x + off];
        }
        __syncthreads();
    }
    if (threadIdx.x < C) {
        atomicAdd(&stats[cidx], ls[threadIdx.x]);
        atomicAdd(&stats[C + cidx], ls2[threadIdx.x]);
    }
}

// BN normalize + emit fp32 out + fp16 xh + t = out@U  (node per thread)
template <int C>
__global__ __launch_bounds__(256) void bn_norm_prep_kernel(const float* __restrict__ a,
                                                           const float* __restrict__ stats,
                                                           const float* __restrict__ g,
                                                           const float* __restrict__ be,
                                                           const float* __restrict__ U,
                                                           float* __restrict__ out,
                                                           _Float16* __restrict__ xh,
                                                           float* __restrict__ t) {
    __shared__ float mS[C], sS[C], beS[C], Us[C * 4];
    if (threadIdx.x < C) {
        int c = threadIdx.x;
        float mean = stats[c] * (1.f / NN);
        float var = stats[C + c] * (1.f / NN) - mean * mean;
        mS[c] = mean;
        sS[c] = rsqrtf(fmaxf(var, 0.f) + 1e-5f) * g[c];
        beS[c] = be[c];
    }
    for (int i = threadIdx.x; i < C * 4; i += 256) Us[i] = U[i];
    __syncthreads();
    int n = blockIdx.x * 256 + threadIdx.x;
    if (n >= NN) return;
    const float4* ap = reinterpret_cast<const float4*>(a + (size_t)n * C);
    float4* op = reinterpret_cast<float4*>(out + (size_t)n * C);
    h8* xo = reinterpret_cast<h8*>(xh + (size_t)n * C);
    float t0 = 0.f, t1 = 0.f, t2 = 0.f, t3 = 0.f;
#pragma unroll
    for (int q8 = 0; q8 < C / 8; q8++) {
        h8 hv;
#pragma unroll
        for (int q4 = 0; q4 < 2; q4++) {
            int c4 = q8 * 2 + q4;
            float4 v = ap[c4];
            float r0 = (v.x - mS[c4 * 4 + 0]) * sS[c4 * 4 + 0] + beS[c4 * 4 + 0];
            float r1 = (v.y - mS[c4 * 4 + 1]) * sS[c4 * 4 + 1] + beS[c4 * 4 + 1];
            float r2 = (v.z - mS[c4 * 4 + 2]) * sS[c4 * 4 + 2] + beS[c4 * 4 + 2];
            float r3 = (v.w - mS[c4 * 4 + 3]) * sS[c4 * 4 + 3] + beS[c4 * 4 + 3];
            op[c4] = make_float4(r0, r1, r2, r3);
            hv[q4 * 4 + 0] = (_Float16)r0; hv[q4 * 4 + 1] = (_Float16)r1;
            hv[q4 * 4 + 2] = (_Float16)r2; hv[q4 * 4 + 3] = (_Float16)r3;
            t0 = fmaf(r0, Us[(c4 * 4 + 0) * 4 + 0], t0); t1 = fmaf(r0, Us[(c4 * 4 + 0) * 4 + 1], t1);
            t2 = fmaf(r0, Us[(c4 * 4 + 0) * 4 + 2], t2); t3 = fmaf(r0, Us[(c4 * 4 + 0) * 4 + 3], t3);
            t0 = fmaf(r1, Us[(c4 * 4 + 1) * 4 + 0], t0); t1 = fmaf(r1, Us[(c4 * 4 + 1) * 4 + 1], t1);
            t2 = fmaf(r1, Us[(c4 * 4 + 1) * 4 + 2], t2); t3 = fmaf(r1, Us[(c4 * 4 + 1) * 4 + 3], t3);
            t0 = fmaf(r2, Us[(c4 * 4 + 2) * 4 + 0], t0); t1 = fmaf(r2, Us[(c4 * 4 + 2) * 4 + 1], t1);
            t2 = fmaf(r2, Us[(c4 * 4 + 2) * 4 + 2], t2); t3 = fmaf(r2, Us[(c4 * 4 + 2) * 4 + 3], t3);
            t0 = fmaf(r3, Us[(c4 * 4 + 3) * 4 + 0], t0); t1 = fmaf(r3, Us[(c4 * 4 + 3) * 4 + 1], t1);
            t2 = fmaf(r3, Us[(c4 * 4 + 3) * 4 + 2], t2); t3 = fmaf(r3, Us[(c4 * 4 + 3) * 4 + 3], t3);
        }
        xo[q8] = hv;
    }
    reinterpret_cast<float4*>(t)[n] = make_float4(t0, t1, t2, t3);
}

template <int C>
__global__ __launch_bounds__(256) void bn_norm_kernel(const float* __restrict__ a,
                                                      const float* __restrict__ stats,
                                                      const float* __restrict__ g,
                                                      const float* __restrict__ be,
                                                      float* __restrict__ out) {
    int i = blockIdx.x * 256 + threadIdx.x;
    if (i >= NN * C) return;
    int cidx = i % C;
    float mean = stats[cidx] * (1.f / NN);
    float var = stats[C + cidx] * (1.f / NN) - mean * mean;
    float sc = rsqrtf(fmaxf(var, 0.f) + 1e-5f) * g[cidx];
    out[i] = (a[i] - mean) * sc + be[cidx];
}

// ------------------------------- MLP head -----------------------------------
__global__ __launch_bounds__(256) void lin1_kernel(const float* __restrict__ x1,
                                                   const float* __restrict__ x2,
                                                   const float* __restrict__ x3,
                                                   const float* __restrict__ lw,
                                                   const float* __restrict__ lb,
                                                   _Float16* __restrict__ z1) {
    __shared__ float Ws[128 * 32];
    int j0 = blockIdx.y * 32;
    for (int i = threadIdx.x; i < 128 * 32; i += 256) {
        int k = i >> 5, jj = i & 31;
        Ws[i] = lw[k * 256 + j0 + jj];
    }
    __syncthreads();
    int n = blockIdx.x * 256 + threadIdx.x;
    if (n >= NN) return;
    float acc[32];
#pragma unroll
    for (int u = 0; u < 32; u++) acc[u] = lb[j0 + u];

    const float4* p1 = reinterpret_cast<const float4*>(x1 + (size_t)n * 32);
#pragma unroll
    for (int q = 0; q < 8; q++) {
        float4 v = p1[q];
        v.x = fmaxf(v.x, 0.f); v.y = fmaxf(v.y, 0.f); v.z = fmaxf(v.z, 0.f); v.w = fmaxf(v.w, 0.f);
        const float* w = &Ws[(q * 4) * 32];
#pragma unroll
        for (int u = 0; u < 32; u++) {
            acc[u] = fmaf(v.x, w[u], acc[u]);
            acc[u] = fmaf(v.y, w[32 + u], acc[u]);
            acc[u] = fmaf(v.z, w[64 + u], acc[u]);
            acc[u] = fmaf(v.w, w[96 + u], acc[u]);
        }
    }
    const float4* p2 = reinterpret_cast<const float4*>(x2 + (size_t)n * 32);
#pragma unroll
    for (int q = 0; q < 8; q++) {
        float4 v = p2[q];
        v.x = fmaxf(v.x, 0.f); v.y = fmaxf(v.y, 0.f); v.z = fmaxf(v.z, 0.f); v.w = fmaxf(v.w, 0.f);
        const float* w = &Ws[(32 + q * 4) * 32];
#pragma unroll
        for (int u = 0; u < 32; u++) {
            acc[u] = fmaf(v.x, w[u], acc[u]);
            acc[u] = fmaf(v.y, w[32 + u], acc[u]);
            acc[u] = fmaf(v.z, w[64 + u], acc[u]);
            acc[u] = fmaf(v.w, w[96 + u], acc[u]);
        }
    }
    const float4* p3 = reinterpret_cast<const float4*>(x3 + (size_t)n * 64);
#pragma unroll
    for (int q = 0; q < 16; q++) {
        float4 v = p3[q];
        v.x = fmaxf(v.x, 0.f); v.y = fmaxf(v.y, 0.f); v.z = fmaxf(v.z, 0.f); v.w = fmaxf(v.w, 0.f);
        const float* w = &Ws[(64 + q * 4) * 32];
#pragma unroll
        for (int u = 0; u < 32; u++) {
            acc[u] = fmaf(v.x, w[u], acc[u]);
            acc[u] = fmaf(v.y, w[32 + u], acc[u]);
            acc[u] = fmaf(v.z, w[64 + u], acc[u]);
            acc[u] = fmaf(v.w, w[96 + u], acc[u]);
        }
    }
    h8* o = reinterpret_cast<h8*>(z1 + (size_t)n * 256 + j0);
#pragma unroll
    for (int q8 = 0; q8 < 4; q8++) {
        h8 hv;
#pragma unroll
        for (int u = 0; u < 8; u++) hv[u] = (_Float16)fmaxf(acc[q8 * 8 + u], 0.f);
        o[q8] = hv;
    }
}

__global__ __launch_bounds__(256) void lin2_kernel(const _Float16* __restrict__ z1,
                                                   const float* __restrict__ lw,
                                                   const float* __restrict__ lb,
                                                   float* __restrict__ z2) {
    __shared__ float Ws[256 * 32];
    int j0 = blockIdx.y * 32;
    for (int i = threadIdx.x; i < 256 * 32; i += 256) {
        int k = i >> 5, jj = i & 31;
        Ws[i] = lw[k * 64 + j0 + jj];
    }
    __syncthreads();
    int n = blockIdx.x * 256 + threadIdx.x;
    if (n >= NN) return;
    float acc[32];
#pragma unroll
    for (int u = 0; u < 32; u++) acc[u] = lb[j0 + u];
    const h8* zp = reinterpret_cast<const h8*>(z1 + (size_t)n * 256);
    for (int k8 = 0; k8 < 32; k8++) {
        h8 v = zp[k8];
#pragma unroll
        for (int u = 0; u < 8; u++) {
            float vf = (float)v[u];
            const float* w = &Ws[(k8 * 8 + u) * 32];
#pragma unroll
            for (int o = 0; o < 32; o++) acc[o] = fmaf(vf, w[o], acc[o]);
        }
    }
    float4* o = reinterpret_cast<float4*>(z2 + (size_t)n * 64 + j0);
#pragma unroll
    for (int u4 = 0; u4 < 8; u4++) {
        o[u4] = make_float4(fmaxf(acc[4 * u4 + 0], 0.f), fmaxf(acc[4 * u4 + 1], 0.f),
                            fmaxf(acc[4 * u4 + 2], 0.f), fmaxf(acc[4 * u4 + 3], 0.f));
    }
}

__global__ __launch_bounds__(256) void lin3o_kernel(const float* __restrict__ z2,
                                                    const float* __restrict__ lw3,
                                                    const float* __restrict__ lb3,
                                                    const float* __restrict__ lwo,
                                                    const float* __restrict__ lbo,
                                                    float* __restrict__ out) {
    __shared__ float W3s[64 * 16];
    __shared__ float Wos[16];
    __shared__ float b3s[16];
    for (int i = threadIdx.x; i < 64 * 16; i += 256) W3s[i] = lw3[i];
    if (threadIdx.x < 16) { Wos[threadIdx.x] = lwo[threadIdx.x]; b3s[threadIdx.x] = lb3[threadIdx.x]; }
    __syncthreads();
    int n = blockIdx.x * 256 + threadIdx.x;
    if (n >= NN) return;
    float acc[16];
#pragma unroll
    for (int u = 0; u < 16; u++) acc[u] = b3s[u];
    const float4* zp = reinterpret_cast<const float4*>(z2 + (size_t)n * 64);
#pragma unroll
    for (int k4 = 0; k4 < 16; k4++) {
        float4 v = zp[k4];
        const float* w = &W3s[(k4 * 4) * 16];
#pragma unroll
        for (int u = 0; u < 16; u++) {
            acc[u] = fmaf(v.x, w[u], acc[u]);
            acc[u] = fmaf(v.y, w[16 + u], acc[u]);
            acc[u] = fmaf(v.z, w[32 + u], acc[u]);
            acc[u] = fmaf(v.w, w[48 + u], acc[u]);
        }
    }
    float s = lbo[0];
#pragma unroll
    for (int u = 0; u < 16; u++) s = fmaf(fmaxf(acc[u], 0.f), Wos[u], s);
    out[n] = 1.f / (1.f + __expf(-s));
}

// ------------------------------- launcher -----------------------------------
extern "C" void kernel_launch(void* const* d_in, const int* in_sizes, int n_in,
                              void* d_out, int out_size, void* d_ws, size_t ws_size,
                              hipStream_t stream) {
    const float* x = (const float*)d_in[0];
    const int* ei = (const int*)d_in[1];
    const int* esrc = ei;
    const int* edst = ei + NE;
    const float* W[6]; const float* U[6]; const float* C[6]; const float* B[6];
    for (int i = 0; i < 6; i++) {
        W[i] = (const float*)d_in[2 + 4 * i];
        U[i] = (const float*)d_in[3 + 4 * i];
        C[i] = (const float*)d_in[4 + 4 * i];
        B[i] = (const float*)d_in[5 + 4 * i];
    }
    const float* g1 = (const float*)d_in[26]; const float* be1 = (const float*)d_in[27];
    const float* g2 = (const float*)d_in[28]; const float* be2 = (const float*)d_in[29];
    const float* g3 = (const float*)d_in[30]; const float* be3 = (const float*)d_in[31];
    const float* lw1 = (const float*)d_in[32]; const float* lb1 = (const float*)d_in[33];
    const float* lw2 = (const float*)d_in[34]; const float* lb2 = (const float*)d_in[35];
    const float* lw3 = (const float*)d_in[36]; const float* lb3 = (const float*)d_in[37];
    const float* lwo = (const float*)d_in[38]; const float* lbo = (const float*)d_in[39];

    char* w = (char*)d_ws;
    size_t o = 0;
    auto take = [&](size_t bytes) -> char* {
        char* p = w + o;
        o = (o + bytes + 255) & ~(size_t)255;
        return p;
    };
    int* deg = (int*)take((size_t)NN * 4);
    int* fillc = (int*)take((size_t)NN * 4);
    float* stats = (float*)take(3 * 256 * 4);
    size_t zero_bytes = o;
    int* row_ptr = (int*)take((size_t)(NN + 1) * 4);
    int* colA = (int*)take((size_t)NE * 4);
    int* dstc = (int*)take((size_t)NE * 4);
    h4v* qbuf = (h4v*)take((size_t)NE * 8);
    float* t = (float*)take((size_t)NN * 4 * 4);
    _Float16* xh = (_Float16*)take((size_t)NN * 32 * 2);
    char* A = take((size_t)NN * 256 * 2);     // y fp16 [N,128] then z1 fp16 [N,256]
    _Float16* y = (_Float16*)A;
    _Float16* z1 = (_Float16*)A;
    float* x1 = (float*)take((size_t)NN * 32 * 4);
    float* x2 = (float*)take((size_t)NN * 32 * 4);
    float* x3 = (float*)take((size_t)NN * 64 * 4);
    float* tmp = (float*)take((size_t)NN * 64 * 4);
    float* z2 = tmp;
    float* st0 = stats, *st1 = stats + 256, *st2 = stats + 512;

    hipMemsetAsync(d_ws, 0, zero_bytes, stream);

    const int EB = (NE + 255) / 256;
    const int NB = (NN + 255) / 256;

    hist_kernel<<<EB, 256, 0, stream>>>(edst, deg);
    scan_kernel<<<1, 1024, 0, stream>>>(deg, row_ptr);
    fill_kernel<<<EB, 256, 0, stream>>>(esrc, edst, row_ptr, fillc, colA, dstc);

    // conv1: 16 -> 16
    prep_kernel<16><<<NB, 256, 0, stream>>>(x, U[0], xh, t);
    edgeq_kernel<<<EB, 256, 0, stream>>>(colA, dstc, t, C[0], qbuf);
    aggB_kernel<16><<<(NN + 15) / 16, 256, 0, stream>>>(xh, qbuf, C[0], row_ptr, colA, y);
    dense_kernel<64, 16, true><<<NB, 256, 0, stream>>>(y, W[0], B[0], U[1], nullptr, xh, t);
    // conv2: 16 -> 32, BN1 -> x1 (+ prep for conv3)
    edgeq_kernel<<<EB, 256, 0, stream>>>(colA, dstc, t, C[1], qbuf);
    aggB_kernel<16><<<(NN + 15) / 16, 256, 0, stream>>>(xh, qbuf, C[1], row_ptr, colA, y);
    dense_kernel<64, 32, false><<<NB, 256, 0, stream>>>(y, W[1], B[1], nullptr, tmp, nullptr, nullptr);
    bn_reduce_kernel<32><<<256, 256, 0, stream>>>(tmp, st0);
    bn_norm_prep_kernel<32><<<NB, 256, 0, stream>>>(tmp, st0, g1, be1, U[2], x1, xh, t);
    // conv3: 32 -> 32
    edgeq_kernel<<<EB, 256, 0, stream>>>(colA, dstc, t, C[2], qbuf);
    aggB_kernel<32><<<(NN + 7) / 8, 256, 0, stream>>>(xh, qbuf, C[2], row_ptr, colA, y);
    dense_kernel<128, 32, true><<<NB, 256, 0, stream>>>(y, W[2], B[2], U[3], nullptr, xh, t);
    // conv4: 32 -> 32, BN2 -> x2 (+ prep for conv5)
    edgeq_kernel<<<EB, 256, 0, stream>>>(colA, dstc, t, C[3], qbuf);
    aggB_kernel<32><<<(NN + 7) / 8, 256, 0, stream>>>(xh, qbuf, C[3], row_ptr, colA, y);
    dense_kernel<128, 32, false><<<NB, 256, 0, stream>>>(y, W[3], B[3], nullptr, tmp, nullptr, nullptr);
    bn_reduce_kernel<32><<<256, 256, 0, stream>>>(tmp, st1);
    bn_norm_prep_kernel<32><<<NB, 256, 0, stream>>>(tmp, st1, g2, be2, U[4], x2, xh, t);
    // conv5: 32 -> 32
    edgeq_kernel<<<EB, 256, 0, stream>>>(colA, dstc, t, C[4], qbuf);
    aggB_kernel<32><<<(NN + 7) / 8, 256, 0, stream>>>(xh, qbuf, C[4], row_ptr, colA, y);
    dense_kernel<128, 32, true><<<NB, 256, 0, stream>>>(y, W[4], B[4], U[5], nullptr, xh, t);
    // conv6: 32 -> 64, BN3 -> x3
    edgeq_kernel<<<EB, 256, 0, stream>>>(colA, dstc, t, C[5], qbuf);
    aggB_kernel<32><<<(NN + 7) / 8, 256, 0, stream>>>(xh, qbuf, C[5], row_ptr, colA, y);
    dense_kernel<128, 64, false><<<NB, 256, 0, stream>>>(y, W[5], B[5], nullptr, tmp, nullptr, nullptr);
    bn_reduce_kernel<64><<<256, 256, 0, stream>>>(tmp, st2);
    bn_norm_kernel<64><<<(NN * 64 + 255) / 256, 256, 0, stream>>>(tmp, st2, g3, be3, x3);

    // MLP head
    lin1_kernel<<<dim3(NB, 8), 256, 0, stream>>>(x1, x2, x3, lw1, lb1, z1);
    lin2_kernel<<<dim3(NB, 2), 256, 0, stream>>>(z1, lw2, lb2, z2);
    lin3o_kernel<<<NB, 256, 0, stream>>>(z2, lw3, lb3, lwo, lbo, (float*)d_out);
}

// Round 6
// 652.784 us; speedup vs baseline: 1.7455x; 1.1532x over previous
//
#include <hip/hip_runtime.h>

constexpr int NN = 50000;   // nodes
constexpr int NE = 800000;  // edges (without self loops)

typedef _Float16 h8 __attribute__((ext_vector_type(8)));
typedef _Float16 h4v __attribute__((ext_vector_type(4)));
typedef float f32x4 __attribute__((ext_vector_type(4)));

// ----------------------------- CSR build -----------------------------------
__global__ void hist_kernel(const int* __restrict__ dst, int* __restrict__ deg) {
    int e = blockIdx.x * blockDim.x + threadIdx.x;
    if (e < NE) atomicAdd(&deg[dst[e]], 1);
}

__global__ __launch_bounds__(1024) void scan_kernel(const int* __restrict__ deg,
                                                    int* __restrict__ row_ptr) {
    __shared__ int wsum[16];
    __shared__ int chunk_total;
    int tid = threadIdx.x, wid = tid >> 6, lane = tid & 63;
    int carry = 0;
    for (int base = 0; base < NN; base += 1024) {
        int i = base + tid;
        int v = (i < NN) ? deg[i] : 0;
        int x = v;
#pragma unroll
        for (int off = 1; off < 64; off <<= 1) {
            int y = __shfl_up(x, off, 64);
            if (lane >= off) x += y;
        }
        if (lane == 63) wsum[wid] = x;
        __syncthreads();
        if (wid == 0) {
            int wv = (lane < 16) ? wsum[lane] : 0;
#pragma unroll
            for (int off = 1; off < 16; off <<= 1) {
                int y = __shfl_up(wv, off, 64);
                if (lane >= off) wv += y;
            }
            if (lane < 16) wsum[lane] = wv;
            if (lane == 15) chunk_total = wv;
        }
        __syncthreads();
        int wprefix = (wid == 0) ? 0 : wsum[wid - 1];
        if (i < NN) row_ptr[i] = carry + wprefix + x - v;  // exclusive
        carry += chunk_total;
        __syncthreads();
    }
    if (tid == 0) row_ptr[NN] = carry;
}

__global__ void fill_kernel(const int* __restrict__ src, const int* __restrict__ dst,
                            const int* __restrict__ row_ptr, int* __restrict__ fillc,
                            int* __restrict__ col, int* __restrict__ dstc) {
    int e = blockIdx.x * blockDim.x + threadIdx.x;
    if (e < NE) {
        int d = dst[e];
        int p = atomicAdd(&fillc[d], 1);
        int k = row_ptr[d] + p;
        col[k] = src[e];
        dstc[k] = d;
    }
}

// -------------- prep (conv1 only): xh = fp16(x), t = x@U --------------------
template <int CI>
__global__ __launch_bounds__(256) void prep_kernel(const float* __restrict__ x,
                                                   const float* __restrict__ U,
                                                   _Float16* __restrict__ xh,
                                                   float* __restrict__ t) {
    __shared__ float Us[CI * 4];
    for (int i = threadIdx.x; i < CI * 4; i += 256) Us[i] = U[i];
    __syncthreads();
    int n = blockIdx.x * 256 + threadIdx.x;
    if (n >= NN) return;
    float xr[CI];
    const float4* xv = reinterpret_cast<const float4*>(x + (size_t)n * CI);
#pragma unroll
    for (int q = 0; q < CI / 4; q++) {
        float4 v = xv[q];
        xr[4 * q + 0] = v.x; xr[4 * q + 1] = v.y; xr[4 * q + 2] = v.z; xr[4 * q + 3] = v.w;
    }
    h8* xo = reinterpret_cast<h8*>(xh + (size_t)n * CI);
#pragma unroll
    for (int q = 0; q < CI / 8; q++) {
        h8 hv;
#pragma unroll
        for (int u = 0; u < 8; u++) hv[u] = (_Float16)xr[8 * q + u];
        xo[q] = hv;
    }
    float a0 = 0.f, a1 = 0.f, a2 = 0.f, a3 = 0.f;
#pragma unroll
    for (int k = 0; k < CI; k++) {
        float xk = xr[k];
        a0 = fmaf(xk, Us[k * 4 + 0], a0); a1 = fmaf(xk, Us[k * 4 + 1], a1);
        a2 = fmaf(xk, Us[k * 4 + 2], a2); a3 = fmaf(xk, Us[k * 4 + 3], a3);
    }
    reinterpret_cast<float4*>(t)[n] = make_float4(a0, a1, a2, a3);
}

// -------------- tU: t = xh @ U (node per thread, fp16 input) ----------------
template <int CO>
__global__ __launch_bounds__(256) void tU_kernel(const _Float16* __restrict__ xh,
                                                 const float* __restrict__ U,
                                                 float* __restrict__ t) {
    __shared__ float Us[CO * 4];
    for (int i = threadIdx.x; i < CO * 4; i += 256) Us[i] = U[i];
    __syncthreads();
    int n = blockIdx.x * 256 + threadIdx.x;
    if (n >= NN) return;
    const h8* xp = reinterpret_cast<const h8*>(xh + (size_t)n * CO);
    float t0 = 0.f, t1 = 0.f, t2 = 0.f, t3 = 0.f;
#pragma unroll
    for (int q8 = 0; q8 < CO / 8; q8++) {
        h8 v = xp[q8];
#pragma unroll
        for (int u = 0; u < 8; u++) {
            float r = (float)v[u];
            const float* us = &Us[(q8 * 8 + u) * 4];
            t0 = fmaf(r, us[0], t0); t1 = fmaf(r, us[1], t1);
            t2 = fmaf(r, us[2], t2); t3 = fmaf(r, us[3], t3);
        }
    }
    reinterpret_cast<float4*>(t)[n] = make_float4(t0, t1, t2, t3);
}

// ----------------- phase A: per-edge softmax weights (fp16 x4) --------------
__global__ __launch_bounds__(256) void edgeq_kernel(const int* __restrict__ col,
                                                    const int* __restrict__ dstc,
                                                    const float* __restrict__ t,
                                                    const float* __restrict__ cvec,
                                                    h4v* __restrict__ qbuf) {
    int k = blockIdx.x * 256 + threadIdx.x;
    if (k >= NE) return;
    int s = col[k], d = dstc[k];
    float4 ts = reinterpret_cast<const float4*>(t)[s];
    float4 td = reinterpret_cast<const float4*>(t)[d];
    float4 cv = *reinterpret_cast<const float4*>(cvec);
    float d0 = ts.x - td.x + cv.x, d1 = ts.y - td.y + cv.y;
    float d2 = ts.z - td.z + cv.z, d3 = ts.w - td.w + cv.w;
    float mm = fmaxf(fmaxf(d0, d1), fmaxf(d2, d3));
    float q0 = __expf(d0 - mm), q1 = __expf(d1 - mm);
    float q2 = __expf(d2 - mm), q3 = __expf(d3 - mm);
    float is = 1.f / (q0 + q1 + q2 + q3);
    h4v q;
    q[0] = (_Float16)(q0 * is); q[1] = (_Float16)(q1 * is);
    q[2] = (_Float16)(q2 * is); q[3] = (_Float16)(q3 * is);
    qbuf[k] = q;
}

// --------- phase B: wave per node; SLOTS edge-slots x CI channels -----------
template <int CI>
__global__ __launch_bounds__(256) void aggC_kernel(const _Float16* __restrict__ xh,
                                                   const h4v* __restrict__ qbuf,
                                                   const float* __restrict__ cvec,
                                                   const int* __restrict__ row_ptr,
                                                   const int* __restrict__ col,
                                                   _Float16* __restrict__ y) {
    constexpr int SLOTS = 64 / CI;
    int lane = threadIdx.x & 63;
    int n = blockIdx.x * 4 + (threadIdx.x >> 6);
    if (n >= NN) return;
    int ch = lane & (CI - 1);
    int slot = lane / CI;
    float4 cv = *reinterpret_cast<const float4*>(cvec);
    float a0 = 0.f, a1 = 0.f, a2 = 0.f, a3 = 0.f;
    if (slot == 0) {
        float m = fmaxf(fmaxf(cv.x, cv.y), fmaxf(cv.z, cv.w));
        float s0 = __expf(cv.x - m), s1 = __expf(cv.y - m),
              s2 = __expf(cv.z - m), s3 = __expf(cv.w - m);
        float sinv = 1.f / (s0 + s1 + s2 + s3);
        float xself = (float)xh[(size_t)n * CI + ch];
        a0 = s0 * sinv * xself; a1 = s1 * sinv * xself;
        a2 = s2 * sinv * xself; a3 = s3 * sinv * xself;
    }
    int beg = row_ptr[n], end = row_ptr[n + 1];
#pragma unroll 4
    for (int e = beg + slot; e < end; e += SLOTS) {
        int s = col[e];
        h4v q = qbuf[e];
        float xv = (float)xh[(size_t)s * CI + ch];
        a0 = fmaf((float)q[0], xv, a0); a1 = fmaf((float)q[1], xv, a1);
        a2 = fmaf((float)q[2], xv, a2); a3 = fmaf((float)q[3], xv, a3);
    }
#pragma unroll
    for (int off = 32; off >= CI; off >>= 1) {
        a0 += __shfl_xor(a0, off); a1 += __shfl_xor(a1, off);
        a2 += __shfl_xor(a2, off); a3 += __shfl_xor(a3, off);
    }
    if (slot == 0) {
        float sc = 1.f / (float)(end - beg + 1);
        _Float16* yo = y + (size_t)n * 4 * CI + ch;
        yo[0]      = (_Float16)(a0 * sc);
        yo[CI]     = (_Float16)(a1 * sc);
        yo[2 * CI] = (_Float16)(a2 * sc);
        yo[3 * CI] = (_Float16)(a3 * sc);
    }
}

// ---------------- MFMA GEMM: out = relu(A @ B + bias) -----------------------
// A: [NN, K] fp16. B from W: STACKED -> B[k][o] = W[k%CIc][(k/CIc)*CO + o]
//                            else      B[k][o] = W[k][o].
// v_mfma_f32_16x16x16f16 fragments: A: row=l&15, k=4*(l>>4)+j
//                                   B: col=l&15, k=4*(l>>4)+j
//                                   C: row=(l>>4)*4+i, col=l&15
template <int K, int CO, int COB, bool STACKED, bool OUT16>
__global__ __launch_bounds__(256) void mfma_dense_kernel(const _Float16* __restrict__ A,
                                                         const float* __restrict__ W,
                                                         const float* __restrict__ bias,
                                                         void* __restrict__ outp) {
    constexpr int KS = K / 16;
    constexpr int OT = COB / 16;
    constexpr int CIc = K / 4;
    __shared__ _Float16 Bf[OT * KS * 64 * 4];
    __shared__ float bS[COB];
    int o0 = blockIdx.y * COB;
    for (int idx = threadIdx.x; idx < OT * KS * 64; idx += 256) {
        int lane = idx & 63;
        int ks = (idx >> 6) % KS;
        int ot = idx / (64 * KS);
        int o = o0 + ot * 16 + (lane & 15);
        int kb = ks * 16 + (lane >> 4) * 4;
        h4v v;
#pragma unroll
        for (int j = 0; j < 4; j++) {
            int k = kb + j;
            float wv;
            if constexpr (STACKED) wv = W[(k % CIc) * (4 * CO) + (k / CIc) * CO + o];
            else                   wv = W[k * CO + o];
            v[j] = (_Float16)wv;
        }
        *reinterpret_cast<h4v*>(&Bf[idx * 4]) = v;
    }
    for (int i = threadIdx.x; i < COB; i += 256) bS[i] = bias[o0 + i];
    __syncthreads();
    int wid = threadIdx.x >> 6, lane = threadIdx.x & 63;
    int row_in = lane & 15;
    int kgrp = lane >> 4;
    for (int mt = blockIdx.x * 4 + wid; mt < NN / 16; mt += gridDim.x * 4) {
        int m0 = mt * 16;
        f32x4 acc[OT];
#pragma unroll
        for (int t = 0; t < OT; t++) acc[t] = {0.f, 0.f, 0.f, 0.f};
        const _Float16* Ab = A + (size_t)(m0 + row_in) * K + kgrp * 4;
#pragma unroll
        for (int ks = 0; ks < KS; ks++) {
            h4v af = *reinterpret_cast<const h4v*>(Ab + ks * 16);
#pragma unroll
            for (int t = 0; t < OT; t++) {
                h4v bf = *reinterpret_cast<const h4v*>(&Bf[((t * KS + ks) * 64 + lane) * 4]);
                acc[t] = __builtin_amdgcn_mfma_f32_16x16x16f16(af, bf, acc[t], 0, 0, 0);
            }
        }
        int orow0 = m0 + kgrp * 4;
#pragma unroll
        for (int t = 0; t < OT; t++) {
            int col = o0 + t * 16 + row_in;
            float b = bS[t * 16 + row_in];
#pragma unroll
            for (int i = 0; i < 4; i++) {
                float v = fmaxf(acc[t][i] + b, 0.f);
                if constexpr (OUT16)
                    ((_Float16*)outp)[(size_t)(orow0 + i) * CO + col] = (_Float16)v;
                else
                    ((float*)outp)[(size_t)(orow0 + i) * CO + col] = v;
            }
        }
    }
}

// ------------------------------- batch norm ---------------------------------
template <int C>
__global__ __launch_bounds__(256) void bn_reduce_kernel(const float* __restrict__ a,
                                                        float* __restrict__ stats) {
    constexpr int R = 256 / C;
    int cidx = threadIdx.x % C;
    int r = threadIdx.x / C;
    float s = 0.f, s2 = 0.f;
    for (int n = blockIdx.x * R + r; n < NN; n += gridDim.x * R) {
        float v = a[(size_t)n * C + cidx];
        s += v; s2 = fmaf(v, v, s2);
    }
    __shared__ float ls[256], ls2[256];
    ls[threadIdx.x] = s; ls2[threadIdx.x] = s2;
    __syncthreads();
    for (int off = 128; off >= C; off >>= 1) {
        if (threadIdx.x < off) {
            ls[threadIdx.x] += ls[threadIdx.x + off];
            ls2[threadIdx.x] += ls2[threadIdx.x + off];
        }
        __syncthreads();
    }
    if (threadIdx.x < C) {
        atomicAdd(&stats[cidx], ls[threadIdx.x]);
        atomicAdd(&stats[C + cidx], ls2[threadIdx.x]);
    }
}

// BN normalize + emit fp16 xh (no relu) + t = bn@U + zh slice (relu, fp16)
template <int C>
__global__ __launch_bounds__(256) void bn_norm_prep_kernel(const float* __restrict__ a,
                                                           const float* __restrict__ stats,
                                                           const float* __restrict__ g,
                                                           const float* __restrict__ be,
                                                           const float* __restrict__ U,
                                                           _Float16* __restrict__ xh,
                                                           float* __restrict__ t,
                                                           _Float16* __restrict__ zh,
                                                           int zoff) {
    __shared__ float mS[C], sS[C], beS[C], Us[C * 4];
    if (threadIdx.x < C) {
        int c = threadIdx.x;
        float mean = stats[c] * (1.f / NN);
        float var = stats[C + c] * (1.f / NN) - mean * mean;
        mS[c] = mean;
        sS[c] = rsqrtf(fmaxf(var, 0.f) + 1e-5f) * g[c];
        beS[c] = be[c];
    }
    for (int i = threadIdx.x; i < C * 4; i += 256) Us[i] = U[i];
    __syncthreads();
    int n = blockIdx.x * 256 + threadIdx.x;
    if (n >= NN) return;
    const float4* ap = reinterpret_cast<const float4*>(a + (size_t)n * C);
    h8* xo = reinterpret_cast<h8*>(xh + (size_t)n * C);
    h8* zo = reinterpret_cast<h8*>(zh + (size_t)n * 128 + zoff);
    float t0 = 0.f, t1 = 0.f, t2 = 0.f, t3 = 0.f;
#pragma unroll
    for (int q8 = 0; q8 < C / 8; q8++) {
        h8 hv, zv;
#pragma unroll
        for (int q4 = 0; q4 < 2; q4++) {
            int c4 = q8 * 2 + q4;
            float4 v = ap[c4];
            float r0 = (v.x - mS[c4 * 4 + 0]) * sS[c4 * 4 + 0] + beS[c4 * 4 + 0];
            float r1 = (v.y - mS[c4 * 4 + 1]) * sS[c4 * 4 + 1] + beS[c4 * 4 + 1];
            float r2 = (v.z - mS[c4 * 4 + 2]) * sS[c4 * 4 + 2] + beS[c4 * 4 + 2];
            float r3 = (v.w - mS[c4 * 4 + 3]) * sS[c4 * 4 + 3] + beS[c4 * 4 + 3];
            hv[q4 * 4 + 0] = (_Float16)r0; hv[q4 * 4 + 1] = (_Float16)r1;
            hv[q4 * 4 + 2] = (_Float16)r2; hv[q4 * 4 + 3] = (_Float16)r3;
            zv[q4 * 4 + 0] = (_Float16)fmaxf(r0, 0.f); zv[q4 * 4 + 1] = (_Float16)fmaxf(r1, 0.f);
            zv[q4 * 4 + 2] = (_Float16)fmaxf(r2, 0.f); zv[q4 * 4 + 3] = (_Float16)fmaxf(r3, 0.f);
            const float* us;
            us = &Us[(c4 * 4 + 0) * 4];
            t0 = fmaf(r0, us[0], t0); t1 = fmaf(r0, us[1], t1); t2 = fmaf(r0, us[2], t2); t3 = fmaf(r0, us[3], t3);
            us = &Us[(c4 * 4 + 1) * 4];
            t0 = fmaf(r1, us[0], t0); t1 = fmaf(r1, us[1], t1); t2 = fmaf(r1, us[2], t2); t3 = fmaf(r1, us[3], t3);
            us = &Us[(c4 * 4 + 2) * 4];
            t0 = fmaf(r2, us[0], t0); t1 = fmaf(r2, us[1], t1); t2 = fmaf(r2, us[2], t2); t3 = fmaf(r2, us[3], t3);
            us = &Us[(c4 * 4 + 3) * 4];
            t0 = fmaf(r3, us[0], t0); t1 = fmaf(r3, us[1], t1); t2 = fmaf(r3, us[2], t2); t3 = fmaf(r3, us[3], t3);
        }
        xo[q8] = hv;
        zo[q8] = zv;
    }
    reinterpret_cast<float4*>(t)[n] = make_float4(t0, t1, t2, t3);
}

// BN normalize (conv6) -> zh[:, 64:128] = fp16(relu(bn))
template <int C>
__global__ __launch_bounds__(256) void bn_norm_z_kernel(const float* __restrict__ a,
                                                        const float* __restrict__ stats,
                                                        const float* __restrict__ g,
                                                        const float* __restrict__ be,
                                                        _Float16* __restrict__ zh,
                                                        int zoff) {
    __shared__ float mS[C], sS[C], beS[C];
    if (threadIdx.x < C) {
        int c = threadIdx.x;
        float mean = stats[c] * (1.f / NN);
        float var = stats[C + c] * (1.f / NN) - mean * mean;
        mS[c] = mean;
        sS[c] = rsqrtf(fmaxf(var, 0.f) + 1e-5f) * g[c];
        beS[c] = be[c];
    }
    __syncthreads();
    int n = blockIdx.x * 256 + threadIdx.x;
    if (n >= NN) return;
    const float4* ap = reinterpret_cast<const float4*>(a + (size_t)n * C);
    h8* zo = reinterpret_cast<h8*>(zh + (size_t)n * 128 + zoff);
#pragma unroll
    for (int q8 = 0; q8 < C / 8; q8++) {
        h8 zv;
#pragma unroll
        for (int q4 = 0; q4 < 2; q4++) {
            int c4 = q8 * 2 + q4;
            float4 v = ap[c4];
            zv[q4 * 4 + 0] = (_Float16)fmaxf((v.x - mS[c4 * 4 + 0]) * sS[c4 * 4 + 0] + beS[c4 * 4 + 0], 0.f);
            zv[q4 * 4 + 1] = (_Float16)fmaxf((v.y - mS[c4 * 4 + 1]) * sS[c4 * 4 + 1] + beS[c4 * 4 + 1], 0.f);
            zv[q4 * 4 + 2] = (_Float16)fmaxf((v.z - mS[c4 * 4 + 2]) * sS[c4 * 4 + 2] + beS[c4 * 4 + 2], 0.f);
            zv[q4 * 4 + 3] = (_Float16)fmaxf((v.w - mS[c4 * 4 + 3]) * sS[c4 * 4 + 3] + beS[c4 * 4 + 3], 0.f);
        }
        zo[q8] = zv;
    }
}

// ---------------- final: z3 = relu(z2@lw3+lb3); out = sigmoid(z3@lwo+lbo) ---
__global__ __launch_bounds__(256) void lin3o_kernel(const _Float16* __restrict__ z2,
                                                    const float* __restrict__ lw3,
                                                    const float* __restrict__ lb3,
                                                    const float* __restrict__ lwo,
                                                    const float* __restrict__ lbo,
                                                    float* __restrict__ out) {
    __shared__ float W3s[64 * 16];
    __shared__ float Wos[16];
    __shared__ float b3s[16];
    for (int i = threadIdx.x; i < 64 * 16; i += 256) W3s[i] = lw3[i];
    if (threadIdx.x < 16) { Wos[threadIdx.x] = lwo[threadIdx.x]; b3s[threadIdx.x] = lb3[threadIdx.x]; }
    __syncthreads();
    int n = blockIdx.x * 256 + threadIdx.x;
    if (n >= NN) return;
    float acc[16];
#pragma unroll
    for (int u = 0; u < 16; u++) acc[u] = b3s[u];
    const h8* zp = reinterpret_cast<const h8*>(z2 + (size_t)n * 64);
#pragma unroll
    for (int k8 = 0; k8 < 8; k8++) {
        h8 v = zp[k8];
#pragma unroll
        for (int u = 0; u < 8; u++) {
            float vf = (float)v[u];
            const float* w = &W3s[(k8 * 8 + u) * 16];
#pragma unroll
            for (int o = 0; o < 16; o++) acc[o] = fmaf(vf, w[o], acc[o]);
        }
    }
    float s = lbo[0];
#pragma unroll
    for (int u = 0; u < 16; u++) s = fmaf(fmaxf(acc[u], 0.f), Wos[u], s);
    out[n] = 1.f / (1.f + __expf(-s));
}

// ------------------------------- launcher -----------------------------------
extern "C" void kernel_launch(void* const* d_in, const int* in_sizes, int n_in,
                              void* d_out, int out_size, void* d_ws, size_t ws_size,
                              hipStream_t stream) {
    const float* x = (const float*)d_in[0];
    const int* ei = (const int*)d_in[1];
    const int* esrc = ei;
    const int* edst = ei + NE;
    const float* W[6]; const float* U[6]; const float* C[6]; const float* B[6];
    for (int i = 0; i < 6; i++) {
        W[i] = (const float*)d_in[2 + 4 * i];
        U[i] = (const float*)d_in[3 + 4 * i];
        C[i] = (const float*)d_in[4 + 4 * i];
        B[i] = (const float*)d_in[5 + 4 * i];
    }
    const float* g1 = (const float*)d_in[26]; const float* be1 = (const float*)d_in[27];
    const float* g2 = (const float*)d_in[28]; const float* be2 = (const float*)d_in[29];
    const float* g3 = (const float*)d_in[30]; const float* be3 = (const float*)d_in[31];
    const float* lw1 = (const float*)d_in[32]; const float* lb1 = (const float*)d_in[33];
    const float* lw2 = (const float*)d_in[34]; const float* lb2 = (const float*)d_in[35];
    const float* lw3 = (const float*)d_in[36]; const float* lb3 = (const float*)d_in[37];
    const float* lwo = (const float*)d_in[38]; const float* lbo = (const float*)d_in[39];

    char* w = (char*)d_ws;
    size_t o = 0;
    auto take = [&](size_t bytes) -> char* {
        char* p = w + o;
        o = (o + bytes + 255) & ~(size_t)255;
        return p;
    };
    int* deg = (int*)take((size_t)NN * 4);
    int* fillc = (int*)take((size_t)NN * 4);
    float* stats = (float*)take(3 * 256 * 4);
    size_t zero_bytes = o;
    int* row_ptr = (int*)take((size_t)(NN + 1) * 4);
    int* colA = (int*)take((size_t)NE * 4);
    int* dstc = (int*)take((size_t)NE * 4);
    h4v* qbuf = (h4v*)take((size_t)NE * 8);
    float* t = (float*)take((size_t)NN * 4 * 4);
    _Float16* xh = (_Float16*)take((size_t)NN * 32 * 2);
    char* A = take((size_t)NN * 256 * 2);     // y fp16 [N,128] then z1h fp16 [N,256]
    _Float16* y = (_Float16*)A;
    _Float16* z1h = (_Float16*)A;
    _Float16* zh = (_Float16*)take((size_t)NN * 128 * 2);
    float* tmp = (float*)take((size_t)NN * 64 * 4);
    _Float16* z2h = (_Float16*)tmp;           // tmp free after bn3
    float* st0 = stats, *st1 = stats + 256, *st2 = stats + 512;

    hipMemsetAsync(d_ws, 0, zero_bytes, stream);

    const int EB = (NE + 255) / 256;
    const int NB = (NN + 255) / 256;
    const int GB = 250;                        // mfma grid.x

    hist_kernel<<<EB, 256, 0, stream>>>(edst, deg);
    scan_kernel<<<1, 1024, 0, stream>>>(deg, row_ptr);
    fill_kernel<<<EB, 256, 0, stream>>>(esrc, edst, row_ptr, fillc, colA, dstc);

    // conv1: 16 -> 16
    prep_kernel<16><<<NB, 256, 0, stream>>>(x, U[0], xh, t);
    edgeq_kernel<<<EB, 256, 0, stream>>>(colA, dstc, t, C[0], qbuf);
    aggC_kernel<16><<<NN / 4, 256, 0, stream>>>(xh, qbuf, C[0], row_ptr, colA, y);
    mfma_dense_kernel<64, 16, 16, true, true><<<dim3(GB, 1), 256, 0, stream>>>(y, W[0], B[0], xh);
    tU_kernel<16><<<NB, 256, 0, stream>>>(xh, U[1], t);
    // conv2: 16 -> 32, BN1 -> xh/t/zh[:,0:32]
    edgeq_kernel<<<EB, 256, 0, stream>>>(colA, dstc, t, C[1], qbuf);
    aggC_kernel<16><<<NN / 4, 256, 0, stream>>>(xh, qbuf, C[1], row_ptr, colA, y);
    mfma_dense_kernel<64, 32, 32, true, false><<<dim3(GB, 1), 256, 0, stream>>>(y, W[1], B[1], tmp);
    bn_reduce_kernel<32><<<256, 256, 0, stream>>>(tmp, st0);
    bn_norm_prep_kernel<32><<<NB, 256, 0, stream>>>(tmp, st0, g1, be1, U[2], xh, t, zh, 0);
    // conv3: 32 -> 32
    edgeq_kernel<<<EB, 256, 0, stream>>>(colA, dstc, t, C[2], qbuf);
    aggC_kernel<32><<<NN / 4, 256, 0, stream>>>(xh, qbuf, C[2], row_ptr, colA, y);
    mfma_dense_kernel<128, 32, 32, true, true><<<dim3(GB, 1), 256, 0, stream>>>(y, W[2], B[2], xh);
    tU_kernel<32><<<NB, 256, 0, stream>>>(xh, U[3], t);
    // conv4: 32 -> 32, BN2 -> xh/t/zh[:,32:64]
    edgeq_kernel<<<EB, 256, 0, stream>>>(colA, dstc, t, C[3], qbuf);
    aggC_kernel<32><<<NN / 4, 256, 0, stream>>>(xh, qbuf, C[3], row_ptr, colA, y);
    mfma_dense_kernel<128, 32, 32, true, false><<<dim3(GB, 1), 256, 0, stream>>>(y, W[3], B[3], tmp);
    bn_reduce_kernel<32><<<256, 256, 0, stream>>>(tmp, st1);
    bn_norm_prep_kernel<32><<<NB, 256, 0, stream>>>(tmp, st1, g2, be2, U[4], xh, t, zh, 32);
    // conv5: 32 -> 32
    edgeq_kernel<<<EB, 256, 0, stream>>>(colA, dstc, t, C[4], qbuf);
    aggC_kernel<32><<<NN / 4, 256, 0, stream>>>(xh, qbuf, C[4], row_ptr, colA, y);
    mfma_dense_kernel<128, 32, 32, true, true><<<dim3(GB, 1), 256, 0, stream>>>(y, W[4], B[4], xh);
    tU_kernel<32><<<NB, 256, 0, stream>>>(xh, U[5], t);
    // conv6: 32 -> 64, BN3 -> zh[:,64:128]
    edgeq_kernel<<<EB, 256, 0, stream>>>(colA, dstc, t, C[5], qbuf);
    aggC_kernel<32><<<NN / 4, 256, 0, stream>>>(xh, qbuf, C[5], row_ptr, colA, y);
    mfma_dense_kernel<128, 64, 64, true, false><<<dim3(GB, 1), 256, 0, stream>>>(y, W[5], B[5], tmp);
    bn_reduce_kernel<64><<<256, 256, 0, stream>>>(tmp, st2);
    bn_norm_z_kernel<64><<<NB, 256, 0, stream>>>(tmp, st2, g3, be3, zh, 64);

    // MLP head
    mfma_dense_kernel<128, 256, 64, false, true><<<dim3(GB, 4), 256, 0, stream>>>(zh, lw1, lb1, z1h);
    mfma_dense_kernel<256, 64, 64, false, true><<<dim3(GB, 1), 256, 0, stream>>>(z1h, lw2, lb2, z2h);
    lin3o_kernel<<<NB, 256, 0, stream>>>(z2h, lw3, lb3, lwo, lbo, (float*)d_out);
}